// Round 4
// baseline (1679.502 us; speedup 1.0000x reference)
//
#include <hip/hip_runtime.h>
#include <hip/hip_bf16.h>
#include <math.h>

#define BSZ   128
#define NENT  512
#define NP1   513
#define DENT  256
#define KDIM  128
#define DIN   1024
#define DF    256
#define HDIM  128
#define SSTEP 64
#define G4    512
#define NEGV  (-1e9f)
#define INV_MAX (1.0f/512.0f)

// ---------------- helpers ----------------
__device__ inline float sigf(float x){ return 1.f/(1.f+__expf(-x)); }
__device__ inline float bf_lo(unsigned u){ return __uint_as_float(u<<16); }
__device__ inline float bf_hi(unsigned u){ return __uint_as_float(u & 0xffff0000u); }
__device__ inline unsigned bfpack(float lo, float hi){
  return (__float_as_uint(hi)&0xffff0000u) | (__float_as_uint(lo)>>16);
}

// ---- 512-thread (8-wave) block reductions (used by ln512) ----
__device__ inline float2 block_reduce2(float x, float y, float* red){
  #pragma unroll
  for(int o=32;o>0;o>>=1){ x += __shfl_down(x,o,64); y += __shfl_down(y,o,64); }
  int w = threadIdx.x>>6;
  __syncthreads();
  if((threadIdx.x&63)==0){ red[w]=x; red[8+w]=y; }
  __syncthreads();
  float sx=0.f, sy=0.f;
  #pragma unroll
  for(int q=0;q<8;q++){ sx+=red[q]; sy+=red[8+q]; }
  return make_float2(sx,sy);
}

// ---- 1024-thread (16-wave) block reductions (lstm_serial) ----
__device__ inline float2 reduce2_16(float x, float y, float* red){
  #pragma unroll
  for(int o=32;o>0;o>>=1){ x += __shfl_down(x,o,64); y += __shfl_down(y,o,64); }
  int w = threadIdx.x>>6;       // 0..15
  __syncthreads();
  if((threadIdx.x&63)==0){ red[w]=x; red[16+w]=y; }
  __syncthreads();
  float sx=0.f, sy=0.f;
  #pragma unroll
  for(int q=0;q<16;q++){ sx+=red[q]; sy+=red[16+q]; }
  return make_float2(sx,sy);
}

__device__ inline void reduce4_16(float a,float b,float c,float d, float* red, float out[4]){
  #pragma unroll
  for(int o=32;o>0;o>>=1){
    a += __shfl_down(a,o,64); b += __shfl_down(b,o,64);
    c += __shfl_down(c,o,64); d += __shfl_down(d,o,64);
  }
  int w = threadIdx.x>>6;
  __syncthreads();
  if((threadIdx.x&63)==0){ red[w]=a; red[16+w]=b; red[32+w]=c; red[48+w]=d; }
  __syncthreads();
  float s0=0.f,s1=0.f,s2=0.f,s3=0.f;
  #pragma unroll
  for(int q=0;q<16;q++){ s0+=red[q]; s1+=red[16+q]; s2+=red[32+q]; s3+=red[48+q]; }
  out[0]=s0; out[1]=s1; out[2]=s2; out[3]=s3;
}

// ---------------- generic tiled GEMM: C[M,N] = act(A[M,K] @ B^T + bias) ----------------
template<bool BKMAJOR, bool RELU, bool KEYMAP>
__global__ __launch_bounds__(256)
void gemm_kernel(const float* __restrict__ A, const float* __restrict__ B,
                 const float* __restrict__ bias, float* __restrict__ C,
                 int M, int N, int K){
  __shared__ float As[16][64];
  __shared__ float Bs[16][64];
  const int bm = blockIdx.x, bn = blockIdx.y;
  const int t = threadIdx.x;
  const int tm = t>>4, tn = t&15;
  float acc[16];
  #pragma unroll
  for(int q=0;q<16;q++) acc[q]=0.f;

  const int ml = t>>2;          // 0..63
  const int kq = (t&3)*4;       // 0,4,8,12

  for(int k0=0;k0<K;k0+=16){
    {
      float4 av = *(const float4*)&A[(size_t)(bm*64+ml)*K + k0 + kq];
      As[kq+0][ml]=av.x; As[kq+1][ml]=av.y; As[kq+2][ml]=av.z; As[kq+3][ml]=av.w;
    }
    if(!BKMAJOR){
      float4 bv = *(const float4*)&B[(size_t)(bn*64+ml)*K + k0 + kq];
      Bs[kq+0][ml]=bv.x; Bs[kq+1][ml]=bv.y; Bs[kq+2][ml]=bv.z; Bs[kq+3][ml]=bv.w;
    } else {
      int kl = t>>4;
      int nq = (t&15)*4;
      float4 bv = *(const float4*)&B[(size_t)(k0+kl)*N + bn*64 + nq];
      *(float4*)&Bs[kl][nq] = bv;
    }
    __syncthreads();
    #pragma unroll
    for(int k=0;k<16;k++){
      float4 a4 = *(const float4*)&As[k][tm<<2];
      float4 b4 = *(const float4*)&Bs[k][tn<<2];
      float av[4] = {a4.x,a4.y,a4.z,a4.w};
      float bv[4] = {b4.x,b4.y,b4.z,b4.w};
      #pragma unroll
      for(int mi=0;mi<4;mi++)
        #pragma unroll
        for(int ni=0;ni<4;ni++)
          acc[mi*4+ni] = fmaf(av[mi], bv[ni], acc[mi*4+ni]);
    }
    __syncthreads();
  }
  #pragma unroll
  for(int mi=0;mi<4;mi++){
    int gm = (bm<<6)+(tm<<2)+mi;
    size_t orow = KEYMAP ? ((size_t)(gm>>9)*NP1 + (gm&511)) : (size_t)gm;
    #pragma unroll
    for(int ni=0;ni<4;ni++){
      int gn = (bn<<6)+(tn<<2)+ni;
      float v = acc[mi*4+ni];
      if(bias) v += bias[gn];
      if(RELU) v = fmaxf(v,0.f);
      C[orow*N + gn] = v;
    }
  }
}

// ---------------- key fixups: end-embedding row + zero row 512 ----------------
__global__ void fixup_end(const int* __restrict__ en, const float* __restrict__ end_emb,
                          float* __restrict__ key){
  int b = blockIdx.x, k = threadIdx.x;  // 128 x 128
  int e = en[b];
  key[((size_t)b*NP1 + NENT)*KDIM + k] = 0.f;
  key[((size_t)b*NP1 + e)*KDIM + k] = end_emb[k];
}

// ---------------- gather selected key rows, scaled ----------------
__global__ void gather_kr(const int* __restrict__ su, const float* __restrict__ key,
                          float* __restrict__ KR){
  int idx = blockIdx.x*256 + threadIdx.x;  // 8192*128
  int r = idx >> 7, k = idx & 127;
  int b = r >> 6;
  int s = su[r];
  KR[idx] = key[((size_t)b*NP1 + s)*KDIM + k] * INV_MAX;
}

// ---------------- c0v[f] = q1_w[f,:] . e2_b ----------------
__global__ void c0_kernel(const float* __restrict__ q1_w, const float* __restrict__ e2_b,
                          float* __restrict__ c0v){
  int f = threadIdx.x; // 1 block x 256
  float acc=0.f;
  for(int d=0;d<DIN;d++) acc = fmaf(q1_w[(size_t)f*DIN+d], e2_b[d], acc);
  c0v[f]=acc;
}

// ---------------- gated exclusive prefix over steps; emits relu(U), s1, ng ----------------
__global__ void prefix_kernel(const float* __restrict__ U0, const float* __restrict__ Q1K,
                              const float* __restrict__ c0v, const float* __restrict__ T1,
                              const int* __restrict__ su, const int* __restrict__ en,
                              const int* __restrict__ sun,
                              float* __restrict__ RU, float* __restrict__ s1,
                              float* __restrict__ ngout){
  int b = blockIdx.x, f = threadIdx.x;    // 128 x 256
  float acc = U0[b*DF+f];
  float c0f = c0v[f];
  float s1a = 0.f, ng = 0.f;
  int enb = en[b], sunb = sun[b];
  for(int j=0;j<SSTEP;j++){
    int r = b*SSTEP+j;
    float q = Q1K[(size_t)r*DF+f];
    float tt = T1[(size_t)r*DF+f];
    RU[(size_t)r*DF+f] = fmaxf(acc,0.f);
    int sj = su[r];
    float g = ((j+1)<=sunb && sj!=enb) ? 1.f : 0.f;
    acc = fmaf(g, q + c0f, acc);
    s1a = fmaf(g, tt, s1a);
    ng += g;
  }
  s1[b*DF+f]=s1a;
  if(f==0) ngout[b]=ng;
}

// ---------------- in-place LayerNorm over rows of 512 ----------------
__global__ __launch_bounds__(512)
void ln512(float* __restrict__ G, const float* __restrict__ gam, const float* __restrict__ bet){
  __shared__ float red[32];
  size_t r = blockIdx.x;
  int j = threadIdx.x;
  float v = G[r*G4+j];
  float2 s = block_reduce2(v, v*v, red);
  float mu = s.x*(1.f/512.f);
  float rs = rsqrtf(s.y*(1.f/512.f) - mu*mu + 1e-5f);
  G[r*G4+j] = (v-mu)*rs*gam[j] + bet[j];
}

// ---------------- serial 2-layer LN-LSTM scan (1 block per batch, 1024 thr) ----------------
// whh0 in LDS bf16 chunk-major; wih1/whh1 half-rows in 8+8 uint4 regs (64 VGPR).
// thread t = (half=t>>9, j=t&511). LDS ~140KB -> 1 block/CU, 4 waves/SIMD, 128-VGPR budget.
__global__ __launch_bounds__(1024)
__attribute__((amdgpu_waves_per_eu(4,4)))
void lstm_serial(const float* __restrict__ wih, const float* __restrict__ whh,
                 const float* __restrict__ G0,
                 const float* __restrict__ ln_ig, const float* __restrict__ ln_ib,
                 const float* __restrict__ ln_hg, const float* __restrict__ ln_hb,
                 const float* __restrict__ ln_cg, const float* __restrict__ ln_cb,
                 float* __restrict__ H1){
  const int b = blockIdx.x;
  const int t = threadIdx.x;
  const int j = t & 511;
  const int half = t >> 9;
  __shared__ uint4 W0s[16][512];       // whh0 bf16, chunk-major: [k-chunk][row]  (128 KB)
  __shared__ float pu[2][512];         // partial-dot exchange
  __shared__ float pv[2][512];
  __shared__ float ash[512];
  __shared__ float h0s[128], h1s[128];
  __shared__ float red[64];

  // stage whh0 half-row j into LDS
  #pragma unroll
  for(int c=0;c<8;c++){
    const float* src = &whh[(size_t)j*KDIM + half*64 + c*8];
    float4 a = *(const float4*)src;
    float4 d = *(const float4*)(src+4);
    uint4 p;
    p.x=bfpack(a.x,a.y); p.y=bfpack(a.z,a.w); p.z=bfpack(d.x,d.y); p.w=bfpack(d.z,d.w);
    W0s[half*8+c][j] = p;
  }
  // register weights: wih1 / whh1 half-rows (8+8 uint4 = 64 VGPR)
  uint4 w1p[8], w2p[8];
  #pragma unroll
  for(int c=0;c<8;c++){
    const float* s1 = &wih[65536 + (size_t)j*KDIM + half*64 + c*8];
    float4 a=*(const float4*)s1, d=*(const float4*)(s1+4);
    w1p[c].x=bfpack(a.x,a.y); w1p[c].y=bfpack(a.z,a.w);
    w1p[c].z=bfpack(d.x,d.y); w1p[c].w=bfpack(d.z,d.w);
    const float* s2 = &whh[65536 + (size_t)j*KDIM + half*64 + c*8];
    float4 e=*(const float4*)s2, f=*(const float4*)(s2+4);
    w2p[c].x=bfpack(e.x,e.y); w2p[c].y=bfpack(e.z,e.w);
    w2p[c].z=bfpack(f.x,f.y); w2p[c].w=bfpack(f.z,f.w);
  }

  const float hg0 = ln_hg[j],     hb0 = ln_hb[j];
  const float ig1 = ln_ig[512+j], ib1 = ln_ib[512+j];
  const float hg1 = ln_hg[512+j], hb1 = ln_hb[512+j];
  float cg0=0.f,cb0=0.f,cg1=0.f,cb1=0.f,c0r=0.f,c1r=0.f;
  if(t<128){ cg0=ln_cg[t]; cb0=ln_cb[t]; cg1=ln_cg[128+t]; cb1=ln_cb[128+t]; h0s[t]=0.f; h1s[t]=0.f; }
  __syncthreads();

  const float4* h04 = (const float4*)h0s;
  const float4* h14 = (const float4*)h1s;

  for(int i=0;i<SSTEP;i++){
    float g0v = G0[((size_t)b*SSTEP+i)*G4 + j];

    // ---- layer 0: partial dot (this thread's 64-wide half) ----
    float vp = 0.f, vq = 0.f;
    #pragma unroll
    for(int c=0;c<8;c++){
      int g = half*8 + c;
      uint4 w = W0s[g][j];
      float4 ha = h04[2*g], hb = h04[2*g+1];
      vp = fmaf(bf_lo(w.x),ha.x,vp); vp = fmaf(bf_hi(w.x),ha.y,vp);
      vp = fmaf(bf_lo(w.y),ha.z,vp); vp = fmaf(bf_hi(w.y),ha.w,vp);
      vq = fmaf(bf_lo(w.z),hb.x,vq); vq = fmaf(bf_hi(w.z),hb.y,vq);
      vq = fmaf(bf_lo(w.w),hb.z,vq); vq = fmaf(bf_hi(w.w),hb.w,vq);
    }
    vp += vq;
    pu[half][j] = vp;
    __syncthreads();
    float vo = pu[half^1][j];
    float vj = vp + vo;                      // full dot for row j (both halves hold it)
    // Σ_t vp = Σ_j v_j ;  Σ_t vp*(vp+vo) = Σ_j v_j²
    float2 s = reduce2_16(vp, vp*vj, red);
    float mu = s.x*(1.f/512.f);
    float rs = rsqrtf(s.y*(1.f/512.f) - mu*mu + 1e-5f);
    ash[j] = g0v + (vj-mu)*rs*hg0 + hb0;     // both halves write same value
    __syncthreads();

    float cpre = 0.f;
    if(t<128){
      float gi=ash[t], gf=ash[t+128], gg=ash[t+256];
      cpre = sigf(gf)*c0r + sigf(gi)*tanhf(gg);
    }
    float2 sc = reduce2_16(cpre, cpre*cpre, red);
    float muc = sc.x*(1.f/128.f);
    float rsc = rsqrtf(sc.y*(1.f/128.f) - muc*muc + 1e-5f);
    if(t<128){
      c0r = (cpre-muc)*rsc*cg0 + cb0;
      h0s[t] = sigf(ash[t+384])*tanhf(c0r);
    }
    __syncthreads();

    // ---- layer 1: u = wih1@h0, v1 = whh1@h1 (partial halves) ----
    float up=0.f, uq=0.f, v1p=0.f, v1q=0.f;
    #pragma unroll
    for(int c=0;c<8;c++){
      int g = half*8 + c;
      uint4 wa = w1p[c];
      uint4 wb = w2p[c];
      float4 ha = h04[2*g], hc = h04[2*g+1];
      float4 ga = h14[2*g], gc = h14[2*g+1];
      up  = fmaf(bf_lo(wa.x),ha.x,up ); up  = fmaf(bf_hi(wa.x),ha.y,up );
      up  = fmaf(bf_lo(wa.y),ha.z,up ); up  = fmaf(bf_hi(wa.y),ha.w,up );
      uq  = fmaf(bf_lo(wa.z),hc.x,uq ); uq  = fmaf(bf_hi(wa.z),hc.y,uq );
      uq  = fmaf(bf_lo(wa.w),hc.z,uq ); uq  = fmaf(bf_hi(wa.w),hc.w,uq );
      v1p = fmaf(bf_lo(wb.x),ga.x,v1p); v1p = fmaf(bf_hi(wb.x),ga.y,v1p);
      v1p = fmaf(bf_lo(wb.y),ga.z,v1p); v1p = fmaf(bf_hi(wb.y),ga.w,v1p);
      v1q = fmaf(bf_lo(wb.z),gc.x,v1q); v1q = fmaf(bf_hi(wb.z),gc.y,v1q);
      v1q = fmaf(bf_lo(wb.w),gc.z,v1q); v1q = fmaf(bf_hi(wb.w),gc.w,v1q);
    }
    up += uq; v1p += v1q;
    pu[half][j] = up;
    pv[half][j] = v1p;
    __syncthreads();
    float uo  = pu[half^1][j];
    float v1o = pv[half^1][j];
    float ujf  = up + uo;
    float v1jf = v1p + v1o;
    float s4[4];
    reduce4_16(up, up*ujf, v1p, v1p*v1jf, red, s4);
    float muu = s4[0]*(1.f/512.f);
    float rsu = rsqrtf(s4[1]*(1.f/512.f) - muu*muu + 1e-5f);
    float muv = s4[2]*(1.f/512.f);
    float rsv = rsqrtf(s4[3]*(1.f/512.f) - muv*muv + 1e-5f);
    ash[j] = (ujf-muu)*rsu*ig1 + ib1 + (v1jf-muv)*rsv*hg1 + hb1;
    __syncthreads();

    float cpre1 = 0.f;
    if(t<128){
      float gi=ash[t], gf=ash[t+128], gg=ash[t+256];
      cpre1 = sigf(gf)*c1r + sigf(gi)*tanhf(gg);
    }
    float2 sc1 = reduce2_16(cpre1, cpre1*cpre1, red);
    float muc1 = sc1.x*(1.f/128.f);
    float rsc1 = rsqrtf(sc1.y*(1.f/128.f) - muc1*muc1 + 1e-5f);
    if(t<128){
      c1r = (cpre1-muc1)*rsc1*cg1 + cb1;
      float h1n = sigf(ash[t+384])*tanhf(c1r);
      h1s[t] = h1n;
      H1[((size_t)b*SSTEP+i)*HDIM + t] = h1n;
    }
    __syncthreads();
  }
}

// ---------------- logits: per-batch H1 @ key^T with mask ----------------
__global__ __launch_bounds__(256)
void logits_kernel(const float* __restrict__ key, const float* __restrict__ H1,
                   const int* __restrict__ en, const int* __restrict__ su,
                   float* __restrict__ out){
  const int b = blockIdx.x;
  __shared__ float HsT[128][68];       // [k][i], padded
  __shared__ int firstsel[NP1];
  for(int t=threadIdx.x; t<SSTEP*HDIM; t+=256){
    int i = t>>7, k = t&127;
    HsT[k][i] = H1[(size_t)b*SSTEP*HDIM + t];
  }
  for(int t=threadIdx.x; t<NP1; t+=256) firstsel[t] = 1<<30;
  __syncthreads();
  if(threadIdx.x < SSTEP) atomicMin(&firstsel[su[b*SSTEP+threadIdx.x]], (int)threadIdx.x);
  __syncthreads();
  const int enb = en[b];
  for(int n=threadIdx.x; n<NP1; n+=256){
    if(n > enb){
      for(int i=0;i<SSTEP;i++) out[((size_t)b*SSTEP+i)*NP1 + n] = NEGV;
      continue;
    }
    const float* kr = key + ((size_t)b*NP1 + n)*KDIM;
    const int fs = firstsel[n];
    for(int it=0; it<SSTEP; it+=16){
      float acc[16];
      #pragma unroll
      for(int q=0;q<16;q++) acc[q]=0.f;
      for(int k=0;k<KDIM;k+=4){
        float4 kv = *(const float4*)&kr[k];
        float kvs[4] = {kv.x,kv.y,kv.z,kv.w};
        #pragma unroll
        for(int kk=0;kk<4;kk++){
          #pragma unroll
          for(int qq=0;qq<4;qq++){
            float4 hv = *(const float4*)&HsT[k+kk][it+qq*4];
            acc[qq*4+0] = fmaf(kvs[kk], hv.x, acc[qq*4+0]);
            acc[qq*4+1] = fmaf(kvs[kk], hv.y, acc[qq*4+1]);
            acc[qq*4+2] = fmaf(kvs[kk], hv.z, acc[qq*4+2]);
            acc[qq*4+3] = fmaf(kvs[kk], hv.w, acc[qq*4+3]);
          }
        }
      }
      #pragma unroll
      for(int q=0;q<16;q++){
        int i = it+q;
        bool m = (fs >= i) && !(i==0 && n==enb);
        out[((size_t)b*SSTEP+i)*NP1 + n] = m ? acc[q] : NEGV;
      }
    }
  }
}

// ---------------- final ae + selected_units_num ----------------
__global__ void ae_out_kernel(const float* __restrict__ emb, const float* __restrict__ P,
                              const float* __restrict__ e2_b, const float* __restrict__ ng,
                              const int* __restrict__ sun, float* __restrict__ out){
  const size_t AE_OFF = (size_t)BSZ*SSTEP*NP1;
  const size_t SUN_OFF = AE_OFF + (size_t)BSZ*DIN;
  int idx = blockIdx.x*256+threadIdx.x;   // 131072
  int b = idx>>10, d = idx&1023;
  out[AE_OFF + idx] = emb[idx] + P[idx] + ng[b]*e2_b[d];
  if(idx < BSZ) out[SUN_OFF + idx] = (float)sun[idx];
}

// ---------------- launch ----------------
extern "C" void kernel_launch(void* const* d_in, const int* in_sizes, int n_in,
                              void* d_out, int out_size, void* d_ws, size_t ws_size,
                              hipStream_t stream){
  const float* emb     = (const float*)d_in[0];
  const float* ent     = (const float*)d_in[1];
  const float* key_w   = (const float*)d_in[2];
  const float* key_b   = (const float*)d_in[3];
  const float* q1_w    = (const float*)d_in[4];
  const float* q1_b    = (const float*)d_in[5];
  const float* q2_w    = (const float*)d_in[6];
  const float* q2_b    = (const float*)d_in[7];
  const float* e1_w    = (const float*)d_in[8];
  const float* e1_b    = (const float*)d_in[9];
  const float* e2_w    = (const float*)d_in[10];
  const float* e2_b    = (const float*)d_in[11];
  const float* end_emb = (const float*)d_in[12];
  const float* wih     = (const float*)d_in[13];
  const float* whh     = (const float*)d_in[14];
  const float* ln_ig   = (const float*)d_in[15];
  const float* ln_ib   = (const float*)d_in[16];
  const float* ln_hg   = (const float*)d_in[17];
  const float* ln_hb   = (const float*)d_in[18];
  const float* ln_cg   = (const float*)d_in[19];
  const float* ln_cb   = (const float*)d_in[20];
  const int* en  = (const int*)d_in[21];
  const int* su  = (const int*)d_in[22];
  const int* sun = (const int*)d_in[23];
  float* out = (float*)d_out;
  float* ws  = (float*)d_ws;

  // workspace layout (float units)
  const size_t o_key = 0;                       // 128*513*128 = 8,404,992
  const size_t o_KR  = o_key + 8404992;         // 1,048,576
  const size_t o_T1  = o_KR  + 1048576;         // 2,097,152
  const size_t o_q1e = o_T1  + 2097152;         // 65,536
  const size_t o_c0  = o_q1e + 65536;           // 1,024 (256 used)
  const size_t o_U0  = o_c0  + 1024;            // 32,768
  const size_t o_Q1K = o_U0  + 32768;           // 2,097,152
  const size_t o_RU  = o_Q1K + 2097152;         // 2,097,152
  const size_t o_X   = o_RU  + 2097152;         // 1,048,576
  const size_t o_G0  = o_X   + 1048576;         // 4,194,304
  const size_t o_s1  = o_G0  + 4194304;         // 32,768
  const size_t o_ng  = o_s1  + 32768;           // 1,024 (128 used)
  const size_t o_H1  = o_ng  + 1024;            // 1,048,576
  const size_t o_P   = o_H1  + 1048576;         // 131,072

  // 1) key = ent_emb @ key_w^T + key_b  (rows mapped into 513-stride layout)
  gemm_kernel<false,false,true><<<dim3(1024,2),256,0,stream>>>(ent, key_w, key_b, ws+o_key, 65536,128,256);
  // 2) end-embedding row + zero row 512
  fixup_end<<<128,128,0,stream>>>(en, end_emb, ws+o_key);
  // 3) gather selected rows / 512
  gather_kr<<<4096,256,0,stream>>>(su, ws+o_key, ws+o_KR);
  // 4) T1 = relu(KR @ e1_w^T + e1_b)
  gemm_kernel<false,true,false><<<dim3(128,4),256,0,stream>>>(ws+o_KR, e1_w, e1_b, ws+o_T1, 8192,256,128);
  // 5) q1e = q1_w @ e2_w   (fused 256x256 weight)
  gemm_kernel<true,false,false><<<dim3(4,4),256,0,stream>>>(q1_w, e2_w, nullptr, ws+o_q1e, 256,256,1024);
  // 6) c0 = q1_w @ e2_b
  c0_kernel<<<1,256,0,stream>>>(q1_w, e2_b, ws+o_c0);
  // 7) U0 = emb @ q1_w^T + q1_b
  gemm_kernel<false,false,false><<<dim3(2,4),256,0,stream>>>(emb, q1_w, q1_b, ws+o_U0, 128,256,1024);
  // 8) Q1K = T1 @ q1e^T
  gemm_kernel<false,false,false><<<dim3(128,4),256,0,stream>>>(ws+o_T1, ws+o_q1e, nullptr, ws+o_Q1K, 8192,256,256);
  // 9) gated exclusive prefix -> relu(U), s1, ng
  prefix_kernel<<<128,256,0,stream>>>(ws+o_U0, ws+o_Q1K, ws+o_c0, ws+o_T1, su, en, sun,
                                      ws+o_RU, ws+o_s1, ws+o_ng);
  // 10) X = RU @ q2_w^T + q2_b
  gemm_kernel<false,false,false><<<dim3(128,2),256,0,stream>>>(ws+o_RU, q2_w, q2_b, ws+o_X, 8192,128,256);
  // 11) G0 = X @ wih0^T ; then in-place LN with ln_ig0/ln_ib0
  gemm_kernel<false,false,false><<<dim3(128,8),256,0,stream>>>(ws+o_X, wih, nullptr, ws+o_G0, 8192,512,128);
  ln512<<<8192,512,0,stream>>>(ws+o_G0, ln_ig, ln_ib);
  // 12) serial LN-LSTM scan -> H1 (whh0 LDS, wih1/whh1 half-rows in regs, 1024 thr)
  lstm_serial<<<128,1024,0,stream>>>(wih, whh, ws+o_G0,
                                     ln_ig, ln_ib, ln_hg, ln_hb, ln_cg, ln_cb, ws+o_H1);
  // 13) logits (masked) directly into d_out
  logits_kernel<<<128,256,0,stream>>>(ws+o_key, ws+o_H1, en, su, out);
  // 14) P = s1 @ e2_w^T ; ae = emb + P + ng*e2_b ; sun passthrough
  gemm_kernel<false,false,false><<<dim3(2,16),256,0,stream>>>(ws+o_s1, e2_w, nullptr, ws+o_P, 128,1024,256);
  ae_out_kernel<<<512,256,0,stream>>>(emb, ws+o_P, e2_b, ws+o_ng, sun, out);
}

// Round 5
// 894.083 us; speedup vs baseline: 1.8785x; 1.8785x over previous
//
#include <hip/hip_runtime.h>
#include <hip/hip_bf16.h>
#include <math.h>

#define BSZ   128
#define NENT  512
#define NP1   513
#define DENT  256
#define KDIM  128
#define DIN   1024
#define DF    256
#define HDIM  128
#define SSTEP 64
#define G4    512
#define NEGV  (-1e9f)
#define INV_MAX (1.0f/512.0f)

typedef float v2f __attribute__((ext_vector_type(2)));

// ---------------- helpers ----------------
__device__ inline float sigf(float x){ return 1.f/(1.f+__expf(-x)); }

// pack 4 floats -> 4 fp8 e4m3 in one dword
__device__ inline unsigned pk8(float4 f){
  int r = 0;
  r = __builtin_amdgcn_cvt_pk_fp8_f32(f.x, f.y, r, false);
  r = __builtin_amdgcn_cvt_pk_fp8_f32(f.z, f.w, r, true);
  return (unsigned)r;
}
// acc += dot(4 fp8 cols in w, h)
__device__ inline float dot4_fp8(unsigned w, float4 h, float acc){
  v2f p = __builtin_amdgcn_cvt_pk_f32_fp8((int)w, false);
  acc = fmaf(p.x, h.x, acc); acc = fmaf(p.y, h.y, acc);
  p = __builtin_amdgcn_cvt_pk_f32_fp8((int)w, true);
  acc = fmaf(p.x, h.z, acc); acc = fmaf(p.y, h.w, acc);
  return acc;
}

// block = 512 threads (8 waves). Returns sums over the block to ALL threads.
__device__ inline float2 block_reduce2(float x, float y, float* red){
  #pragma unroll
  for(int o=32;o>0;o>>=1){ x += __shfl_down(x,o,64); y += __shfl_down(y,o,64); }
  int w = threadIdx.x>>6;
  __syncthreads();
  if((threadIdx.x&63)==0){ red[w]=x; red[8+w]=y; }
  __syncthreads();
  float sx=0.f, sy=0.f;
  #pragma unroll
  for(int q=0;q<8;q++){ sx+=red[q]; sy+=red[8+q]; }
  return make_float2(sx,sy);
}

__device__ inline void block_reduce4(float a,float b,float c,float d, float* red, float out[4]){
  #pragma unroll
  for(int o=32;o>0;o>>=1){
    a += __shfl_down(a,o,64); b += __shfl_down(b,o,64);
    c += __shfl_down(c,o,64); d += __shfl_down(d,o,64);
  }
  int w = threadIdx.x>>6;
  __syncthreads();
  if((threadIdx.x&63)==0){ red[w]=a; red[8+w]=b; red[16+w]=c; red[24+w]=d; }
  __syncthreads();
  float s0=0.f,s1=0.f,s2=0.f,s3=0.f;
  #pragma unroll
  for(int q=0;q<8;q++){ s0+=red[q]; s1+=red[8+q]; s2+=red[16+q]; s3+=red[24+q]; }
  out[0]=s0; out[1]=s1; out[2]=s2; out[3]=s3;
}

// ---------------- generic tiled GEMM: C[M,N] = act(A[M,K] @ B^T + bias) ----------------
template<bool BKMAJOR, bool RELU, bool KEYMAP>
__global__ __launch_bounds__(256)
void gemm_kernel(const float* __restrict__ A, const float* __restrict__ B,
                 const float* __restrict__ bias, float* __restrict__ C,
                 int M, int N, int K){
  __shared__ float As[16][64];
  __shared__ float Bs[16][64];
  const int bm = blockIdx.x, bn = blockIdx.y;
  const int t = threadIdx.x;
  const int tm = t>>4, tn = t&15;
  float acc[16];
  #pragma unroll
  for(int q=0;q<16;q++) acc[q]=0.f;

  const int ml = t>>2;          // 0..63
  const int kq = (t&3)*4;       // 0,4,8,12

  for(int k0=0;k0<K;k0+=16){
    {
      float4 av = *(const float4*)&A[(size_t)(bm*64+ml)*K + k0 + kq];
      As[kq+0][ml]=av.x; As[kq+1][ml]=av.y; As[kq+2][ml]=av.z; As[kq+3][ml]=av.w;
    }
    if(!BKMAJOR){
      float4 bv = *(const float4*)&B[(size_t)(bn*64+ml)*K + k0 + kq];
      Bs[kq+0][ml]=bv.x; Bs[kq+1][ml]=bv.y; Bs[kq+2][ml]=bv.z; Bs[kq+3][ml]=bv.w;
    } else {
      int kl = t>>4;
      int nq = (t&15)*4;
      float4 bv = *(const float4*)&B[(size_t)(k0+kl)*N + bn*64 + nq];
      *(float4*)&Bs[kl][nq] = bv;
    }
    __syncthreads();
    #pragma unroll
    for(int k=0;k<16;k++){
      float4 a4 = *(const float4*)&As[k][tm<<2];
      float4 b4 = *(const float4*)&Bs[k][tn<<2];
      float av[4] = {a4.x,a4.y,a4.z,a4.w};
      float bv[4] = {b4.x,b4.y,b4.z,b4.w};
      #pragma unroll
      for(int mi=0;mi<4;mi++)
        #pragma unroll
        for(int ni=0;ni<4;ni++)
          acc[mi*4+ni] = fmaf(av[mi], bv[ni], acc[mi*4+ni]);
    }
    __syncthreads();
  }
  #pragma unroll
  for(int mi=0;mi<4;mi++){
    int gm = (bm<<6)+(tm<<2)+mi;
    size_t orow = KEYMAP ? ((size_t)(gm>>9)*NP1 + (gm&511)) : (size_t)gm;
    #pragma unroll
    for(int ni=0;ni<4;ni++){
      int gn = (bn<<6)+(tn<<2)+ni;
      float v = acc[mi*4+ni];
      if(bias) v += bias[gn];
      if(RELU) v = fmaxf(v,0.f);
      C[orow*N + gn] = v;
    }
  }
}

// ---------------- key fixups: end-embedding row + zero row 512 ----------------
__global__ void fixup_end(const int* __restrict__ en, const float* __restrict__ end_emb,
                          float* __restrict__ key){
  int b = blockIdx.x, k = threadIdx.x;  // 128 x 128
  int e = en[b];
  key[((size_t)b*NP1 + NENT)*KDIM + k] = 0.f;
  key[((size_t)b*NP1 + e)*KDIM + k] = end_emb[k];
}

// ---------------- gather selected key rows, scaled ----------------
__global__ void gather_kr(const int* __restrict__ su, const float* __restrict__ key,
                          float* __restrict__ KR){
  int idx = blockIdx.x*256 + threadIdx.x;  // 8192*128
  int r = idx >> 7, k = idx & 127;
  int b = r >> 6;
  int s = su[r];
  KR[idx] = key[((size_t)b*NP1 + s)*KDIM + k] * INV_MAX;
}

// ---------------- c0v[f] = q1_w[f,:] . e2_b ----------------
__global__ void c0_kernel(const float* __restrict__ q1_w, const float* __restrict__ e2_b,
                          float* __restrict__ c0v){
  int f = threadIdx.x; // 1 block x 256
  float acc=0.f;
  for(int d=0;d<DIN;d++) acc = fmaf(q1_w[(size_t)f*DIN+d], e2_b[d], acc);
  c0v[f]=acc;
}

// ---------------- gated exclusive prefix over steps; emits relu(U), s1, ng ----------------
__global__ void prefix_kernel(const float* __restrict__ U0, const float* __restrict__ Q1K,
                              const float* __restrict__ c0v, const float* __restrict__ T1,
                              const int* __restrict__ su, const int* __restrict__ en,
                              const int* __restrict__ sun,
                              float* __restrict__ RU, float* __restrict__ s1,
                              float* __restrict__ ngout){
  int b = blockIdx.x, f = threadIdx.x;    // 128 x 256
  float acc = U0[b*DF+f];
  float c0f = c0v[f];
  float s1a = 0.f, ng = 0.f;
  int enb = en[b], sunb = sun[b];
  for(int j=0;j<SSTEP;j++){
    int r = b*SSTEP+j;
    float q = Q1K[(size_t)r*DF+f];
    float tt = T1[(size_t)r*DF+f];
    RU[(size_t)r*DF+f] = fmaxf(acc,0.f);
    int sj = su[r];
    float g = ((j+1)<=sunb && sj!=enb) ? 1.f : 0.f;
    acc = fmaf(g, q + c0f, acc);
    s1a = fmaf(g, tt, s1a);
    ng += g;
  }
  s1[b*DF+f]=s1a;
  if(f==0) ngout[b]=ng;
}

// ---------------- in-place LayerNorm over rows of 512 ----------------
__global__ __launch_bounds__(512)
void ln512(float* __restrict__ G, const float* __restrict__ gam, const float* __restrict__ bet){
  __shared__ float red[32];
  size_t r = blockIdx.x;
  int j = threadIdx.x;
  float v = G[r*G4+j];
  float2 s = block_reduce2(v, v*v, red);
  float mu = s.x*(1.f/512.f);
  float rs = rsqrtf(s.y*(1.f/512.f) - mu*mu + 1e-5f);
  G[r*G4+j] = (v-mu)*rs*gam[j] + bet[j];
}

// ---------------- serial 2-layer LN-LSTM scan (1 block per batch, 512 thr) ----------------
// whh0 + wih1 in LDS as fp8 chunk-major (64KB each, conflict-free b128);
// whh1 row in 8 uint4 fp8 regs (32 VGPR). Total reg demand ~75 << 128 grant -> no spill.
__global__ __launch_bounds__(512)
__attribute__((amdgpu_waves_per_eu(2,2)))
void lstm_serial(const float* __restrict__ wih, const float* __restrict__ whh,
                 const float* __restrict__ G0,
                 const float* __restrict__ ln_ig, const float* __restrict__ ln_ib,
                 const float* __restrict__ ln_hg, const float* __restrict__ ln_hb,
                 const float* __restrict__ ln_cg, const float* __restrict__ ln_cb,
                 float* __restrict__ H1){
  const int b = blockIdx.x;
  const int j = threadIdx.x;
  __shared__ uint4 W0s8[8][512];       // whh0 fp8, [k-chunk of 16][row]  (64 KB)
  __shared__ uint4 W1s8[8][512];       // wih1 fp8                         (64 KB)
  __shared__ float h0s[128], h1s[128], ash[512];
  __shared__ float red[32];

  // one-time staging: fp8-pack row j of whh0 -> LDS, wih1 -> LDS, whh1 -> regs
  #pragma unroll
  for(int c=0;c<8;c++){
    const float* s0 = &whh[(size_t)j*KDIM + c*16];
    uint4 p;
    p.x = pk8(*(const float4*)(s0+ 0));
    p.y = pk8(*(const float4*)(s0+ 4));
    p.z = pk8(*(const float4*)(s0+ 8));
    p.w = pk8(*(const float4*)(s0+12));
    W0s8[c][j] = p;
    const float* s1 = &wih[65536 + (size_t)j*KDIM + c*16];
    uint4 q;
    q.x = pk8(*(const float4*)(s1+ 0));
    q.y = pk8(*(const float4*)(s1+ 4));
    q.z = pk8(*(const float4*)(s1+ 8));
    q.w = pk8(*(const float4*)(s1+12));
    W1s8[c][j] = q;
  }
  uint4 w2p[8];
  #pragma unroll
  for(int c=0;c<8;c++){
    const float* s2 = &whh[65536 + (size_t)j*KDIM + c*16];
    w2p[c].x = pk8(*(const float4*)(s2+ 0));
    w2p[c].y = pk8(*(const float4*)(s2+ 4));
    w2p[c].z = pk8(*(const float4*)(s2+ 8));
    w2p[c].w = pk8(*(const float4*)(s2+12));
  }

  const float hg0 = ln_hg[j],     hb0 = ln_hb[j];
  const float ig1 = ln_ig[512+j], ib1 = ln_ib[512+j];
  const float hg1 = ln_hg[512+j], hb1 = ln_hb[512+j];
  float cg0=0.f,cb0=0.f,cg1=0.f,cb1=0.f,c0r=0.f,c1r=0.f;
  if(j<128){ cg0=ln_cg[j]; cb0=ln_cb[j]; cg1=ln_cg[128+j]; cb1=ln_cb[128+j]; h0s[j]=0.f; h1s[j]=0.f; }
  __syncthreads();

  const float4* h04 = (const float4*)h0s;
  const float4* h14 = (const float4*)h1s;

  for(int i=0;i<SSTEP;i++){
    float g0v = G0[((size_t)b*SSTEP+i)*G4 + j];

    // ---- layer 0: v = whh0 @ h0 ----
    float v = 0.f, vb = 0.f;
    #pragma unroll
    for(int c=0;c<8;c++){
      uint4 w = W0s8[c][j];
      v  = dot4_fp8(w.x, h04[4*c+0], v );
      vb = dot4_fp8(w.y, h04[4*c+1], vb);
      v  = dot4_fp8(w.z, h04[4*c+2], v );
      vb = dot4_fp8(w.w, h04[4*c+3], vb);
    }
    v += vb;
    float2 s = block_reduce2(v, v*v, red);
    float mu = s.x*(1.f/512.f);
    float rs = rsqrtf(s.y*(1.f/512.f) - mu*mu + 1e-5f);
    ash[j] = g0v + (v-mu)*rs*hg0 + hb0;
    __syncthreads();
    float cpre = 0.f;
    if(j<128){
      float gi=ash[j], gf=ash[j+128], gg=ash[j+256];
      cpre = sigf(gf)*c0r + sigf(gi)*tanhf(gg);
    }
    float2 sc = block_reduce2(j<128?cpre:0.f, j<128?cpre*cpre:0.f, red);
    float muc = sc.x*(1.f/128.f);
    float rsc = rsqrtf(sc.y*(1.f/128.f) - muc*muc + 1e-5f);
    if(j<128){
      c0r = (cpre-muc)*rsc*cg0 + cb0;
      h0s[j] = sigf(ash[j+384])*tanhf(c0r);
    }
    __syncthreads();

    // ---- layer 1: u = wih1 @ h0 (LDS), v1 = whh1 @ h1 (regs) ----
    float u=0.f, ub=0.f, v1=0.f, v1b=0.f;
    #pragma unroll
    for(int c=0;c<8;c++){
      uint4 wa = W1s8[c][j];
      u  = dot4_fp8(wa.x, h04[4*c+0], u );
      ub = dot4_fp8(wa.y, h04[4*c+1], ub);
      u  = dot4_fp8(wa.z, h04[4*c+2], u );
      ub = dot4_fp8(wa.w, h04[4*c+3], ub);
      uint4 wb = w2p[c];
      v1  = dot4_fp8(wb.x, h14[4*c+0], v1 );
      v1b = dot4_fp8(wb.y, h14[4*c+1], v1b);
      v1  = dot4_fp8(wb.z, h14[4*c+2], v1 );
      v1b = dot4_fp8(wb.w, h14[4*c+3], v1b);
    }
    u += ub; v1 += v1b;
    float s4[4];
    block_reduce4(u,u*u,v1,v1*v1,red,s4);
    float muu = s4[0]*(1.f/512.f);
    float rsu = rsqrtf(s4[1]*(1.f/512.f) - muu*muu + 1e-5f);
    float muv = s4[2]*(1.f/512.f);
    float rsv = rsqrtf(s4[3]*(1.f/512.f) - muv*muv + 1e-5f);
    ash[j] = (u-muu)*rsu*ig1 + ib1 + (v1-muv)*rsv*hg1 + hb1;
    __syncthreads();
    float cpre1 = 0.f;
    if(j<128){
      float gi=ash[j], gf=ash[j+128], gg=ash[j+256];
      cpre1 = sigf(gf)*c1r + sigf(gi)*tanhf(gg);
    }
    float2 sc1 = block_reduce2(j<128?cpre1:0.f, j<128?cpre1*cpre1:0.f, red);
    float muc1 = sc1.x*(1.f/128.f);
    float rsc1 = rsqrtf(sc1.y*(1.f/128.f) - muc1*muc1 + 1e-5f);
    if(j<128){
      c1r = (cpre1-muc1)*rsc1*cg1 + cb1;
      float h1n = sigf(ash[j+384])*tanhf(c1r);
      h1s[j] = h1n;
      H1[((size_t)b*SSTEP+i)*HDIM + j] = h1n;
    }
    __syncthreads();
  }
}

// ---------------- logits: per-batch H1 @ key^T with mask ----------------
__global__ __launch_bounds__(256)
void logits_kernel(const float* __restrict__ key, const float* __restrict__ H1,
                   const int* __restrict__ en, const int* __restrict__ su,
                   float* __restrict__ out){
  const int b = blockIdx.x;
  __shared__ float HsT[128][68];       // [k][i], padded
  __shared__ int firstsel[NP1];
  for(int t=threadIdx.x; t<SSTEP*HDIM; t+=256){
    int i = t>>7, k = t&127;
    HsT[k][i] = H1[(size_t)b*SSTEP*HDIM + t];
  }
  for(int t=threadIdx.x; t<NP1; t+=256) firstsel[t] = 1<<30;
  __syncthreads();
  if(threadIdx.x < SSTEP) atomicMin(&firstsel[su[b*SSTEP+threadIdx.x]], (int)threadIdx.x);
  __syncthreads();
  const int enb = en[b];
  for(int n=threadIdx.x; n<NP1; n+=256){
    if(n > enb){
      for(int i=0;i<SSTEP;i++) out[((size_t)b*SSTEP+i)*NP1 + n] = NEGV;
      continue;
    }
    const float* kr = key + ((size_t)b*NP1 + n)*KDIM;
    const int fs = firstsel[n];
    for(int it=0; it<SSTEP; it+=16){
      float acc[16];
      #pragma unroll
      for(int q=0;q<16;q++) acc[q]=0.f;
      for(int k=0;k<KDIM;k+=4){
        float4 kv = *(const float4*)&kr[k];
        float kvs[4] = {kv.x,kv.y,kv.z,kv.w};
        #pragma unroll
        for(int kk=0;kk<4;kk++){
          #pragma unroll
          for(int qq=0;qq<4;qq++){
            float4 hv = *(const float4*)&HsT[k+kk][it+qq*4];
            acc[qq*4+0] = fmaf(kvs[kk], hv.x, acc[qq*4+0]);
            acc[qq*4+1] = fmaf(kvs[kk], hv.y, acc[qq*4+1]);
            acc[qq*4+2] = fmaf(kvs[kk], hv.z, acc[qq*4+2]);
            acc[qq*4+3] = fmaf(kvs[kk], hv.w, acc[qq*4+3]);
          }
        }
      }
      #pragma unroll
      for(int q=0;q<16;q++){
        int i = it+q;
        bool m = (fs >= i) && !(i==0 && n==enb);
        out[((size_t)b*SSTEP+i)*NP1 + n] = m ? acc[q] : NEGV;
      }
    }
  }
}

// ---------------- final ae + selected_units_num ----------------
__global__ void ae_out_kernel(const float* __restrict__ emb, const float* __restrict__ P,
                              const float* __restrict__ e2_b, const float* __restrict__ ng,
                              const int* __restrict__ sun, float* __restrict__ out){
  const size_t AE_OFF = (size_t)BSZ*SSTEP*NP1;
  const size_t SUN_OFF = AE_OFF + (size_t)BSZ*DIN;
  int idx = blockIdx.x*256+threadIdx.x;   // 131072
  int b = idx>>10, d = idx&1023;
  out[AE_OFF + idx] = emb[idx] + P[idx] + ng[b]*e2_b[d];
  if(idx < BSZ) out[SUN_OFF + idx] = (float)sun[idx];
}

// ---------------- launch ----------------
extern "C" void kernel_launch(void* const* d_in, const int* in_sizes, int n_in,
                              void* d_out, int out_size, void* d_ws, size_t ws_size,
                              hipStream_t stream){
  const float* emb     = (const float*)d_in[0];
  const float* ent     = (const float*)d_in[1];
  const float* key_w   = (const float*)d_in[2];
  const float* key_b   = (const float*)d_in[3];
  const float* q1_w    = (const float*)d_in[4];
  const float* q1_b    = (const float*)d_in[5];
  const float* q2_w    = (const float*)d_in[6];
  const float* q2_b    = (const float*)d_in[7];
  const float* e1_w    = (const float*)d_in[8];
  const float* e1_b    = (const float*)d_in[9];
  const float* e2_w    = (const float*)d_in[10];
  const float* e2_b    = (const float*)d_in[11];
  const float* end_emb = (const float*)d_in[12];
  const float* wih     = (const float*)d_in[13];
  const float* whh     = (const float*)d_in[14];
  const float* ln_ig   = (const float*)d_in[15];
  const float* ln_ib   = (const float*)d_in[16];
  const float* ln_hg   = (const float*)d_in[17];
  const float* ln_hb   = (const float*)d_in[18];
  const float* ln_cg   = (const float*)d_in[19];
  const float* ln_cb   = (const float*)d_in[20];
  const int* en  = (const int*)d_in[21];
  const int* su  = (const int*)d_in[22];
  const int* sun = (const int*)d_in[23];
  float* out = (float*)d_out;
  float* ws  = (float*)d_ws;

  // workspace layout (float units)
  const size_t o_key = 0;                       // 128*513*128 = 8,404,992
  const size_t o_KR  = o_key + 8404992;         // 1,048,576
  const size_t o_T1  = o_KR  + 1048576;         // 2,097,152
  const size_t o_q1e = o_T1  + 2097152;         // 65,536
  const size_t o_c0  = o_q1e + 65536;           // 1,024 (256 used)
  const size_t o_U0  = o_c0  + 1024;            // 32,768
  const size_t o_Q1K = o_U0  + 32768;           // 2,097,152
  const size_t o_RU  = o_Q1K + 2097152;         // 2,097,152
  const size_t o_X   = o_RU  + 2097152;         // 1,048,576
  const size_t o_G0  = o_X   + 1048576;         // 4,194,304
  const size_t o_s1  = o_G0  + 4194304;         // 32,768
  const size_t o_ng  = o_s1  + 32768;           // 1,024 (128 used)
  const size_t o_H1  = o_ng  + 1024;            // 1,048,576
  const size_t o_P   = o_H1  + 1048576;         // 131,072

  // 1) key = ent_emb @ key_w^T + key_b  (rows mapped into 513-stride layout)
  gemm_kernel<false,false,true><<<dim3(1024,2),256,0,stream>>>(ent, key_w, key_b, ws+o_key, 65536,128,256);
  // 2) end-embedding row + zero row 512
  fixup_end<<<128,128,0,stream>>>(en, end_emb, ws+o_key);
  // 3) gather selected rows / 512
  gather_kr<<<4096,256,0,stream>>>(su, ws+o_key, ws+o_KR);
  // 4) T1 = relu(KR @ e1_w^T + e1_b)
  gemm_kernel<false,true,false><<<dim3(128,4),256,0,stream>>>(ws+o_KR, e1_w, e1_b, ws+o_T1, 8192,256,128);
  // 5) q1e = q1_w @ e2_w   (fused 256x256 weight)
  gemm_kernel<true,false,false><<<dim3(4,4),256,0,stream>>>(q1_w, e2_w, nullptr, ws+o_q1e, 256,256,1024);
  // 6) c0 = q1_w @ e2_b
  c0_kernel<<<1,256,0,stream>>>(q1_w, e2_b, ws+o_c0);
  // 7) U0 = emb @ q1_w^T + q1_b
  gemm_kernel<false,false,false><<<dim3(2,4),256,0,stream>>>(emb, q1_w, q1_b, ws+o_U0, 128,256,1024);
  // 8) Q1K = T1 @ q1e^T
  gemm_kernel<false,false,false><<<dim3(128,4),256,0,stream>>>(ws+o_T1, ws+o_q1e, nullptr, ws+o_Q1K, 8192,256,256);
  // 9) gated exclusive prefix -> relu(U), s1, ng
  prefix_kernel<<<128,256,0,stream>>>(ws+o_U0, ws+o_Q1K, ws+o_c0, ws+o_T1, su, en, sun,
                                      ws+o_RU, ws+o_s1, ws+o_ng);
  // 10) X = RU @ q2_w^T + q2_b
  gemm_kernel<false,false,false><<<dim3(128,2),256,0,stream>>>(ws+o_RU, q2_w, q2_b, ws+o_X, 8192,128,256);
  // 11) G0 = X @ wih0^T ; then in-place LN with ln_ig0/ln_ib0
  gemm_kernel<false,false,false><<<dim3(128,8),256,0,stream>>>(ws+o_X, wih, nullptr, ws+o_G0, 8192,512,128);
  ln512<<<8192,512,0,stream>>>(ws+o_G0, ln_ig, ln_ib);
  // 12) serial LN-LSTM scan -> H1 (whh0+wih1 fp8 LDS, whh1 fp8 regs)
  lstm_serial<<<128,512,0,stream>>>(wih, whh, ws+o_G0,
                                    ln_ig, ln_ib, ln_hg, ln_hb, ln_cg, ln_cb, ws+o_H1);
  // 13) logits (masked) directly into d_out
  logits_kernel<<<128,256,0,stream>>>(ws+o_key, ws+o_H1, en, su, out);
  // 14) P = s1 @ e2_w^T ; ae = emb + P + ng*e2_b ; sun passthrough
  gemm_kernel<false,false,false><<<dim3(2,16),256,0,stream>>>(ws+o_s1, e2_w, nullptr, ws+o_P, 128,1024,256);
  ae_out_kernel<<<512,256,0,stream>>>(emb, ws+o_P, e2_b, ws+o_ng, sun, out);
}

// Round 7
// 764.478 us; speedup vs baseline: 2.1969x; 1.1695x over previous
//
#include <hip/hip_runtime.h>
#include <hip/hip_bf16.h>
#include <math.h>

#define BSZ   128
#define NENT  512
#define NP1   513
#define DENT  256
#define KDIM  128
#define DIN   1024
#define DF    256
#define HDIM  128
#define SSTEP 64
#define G4    512
#define NEGV  (-1e9f)
#define INV_MAX (1.0f/512.0f)

typedef float v2f __attribute__((ext_vector_type(2)));

// ---------------- helpers ----------------
__device__ inline float sigf(float x){ return 1.f/(1.f+__expf(-x)); }
__device__ inline float tanh_fast(float x){ float e=__expf(2.f*x); return 1.f - 2.f/(e+1.f); }

// pack 4 floats -> 4 fp8 e4m3 in one dword
__device__ inline unsigned pk8(float4 f){
  int r = 0;
  r = __builtin_amdgcn_cvt_pk_fp8_f32(f.x, f.y, r, false);
  r = __builtin_amdgcn_cvt_pk_fp8_f32(f.z, f.w, r, true);
  return (unsigned)r;
}
// acc += dot(4 fp8 cols in w, h)
__device__ inline float dot4_fp8(unsigned w, float4 h, float acc){
  v2f p = __builtin_amdgcn_cvt_pk_f32_fp8((int)w, false);
  acc = fmaf(p.x, h.x, acc); acc = fmaf(p.y, h.y, acc);
  p = __builtin_amdgcn_cvt_pk_f32_fp8((int)w, true);
  acc = fmaf(p.x, h.z, acc); acc = fmaf(p.y, h.w, acc);
  return acc;
}

// block = 512 threads (8 waves). Returns sums over the block to ALL threads.
__device__ inline float2 block_reduce2(float x, float y, float* red){
  #pragma unroll
  for(int o=32;o>0;o>>=1){ x += __shfl_down(x,o,64); y += __shfl_down(y,o,64); }
  int w = threadIdx.x>>6;
  __syncthreads();
  if((threadIdx.x&63)==0){ red[w]=x; red[8+w]=y; }
  __syncthreads();
  float sx=0.f, sy=0.f;
  #pragma unroll
  for(int q=0;q<8;q++){ sx+=red[q]; sy+=red[8+q]; }
  return make_float2(sx,sy);
}

// ---------------- generic tiled GEMM: C[M,N] = act(A[M,K] @ B^T + bias) ----------------
template<bool BKMAJOR, bool RELU, bool KEYMAP>
__global__ __launch_bounds__(256)
void gemm_kernel(const float* __restrict__ A, const float* __restrict__ B,
                 const float* __restrict__ bias, float* __restrict__ C,
                 int M, int N, int K){
  __shared__ float As[16][64];
  __shared__ float Bs[16][64];
  const int bm = blockIdx.x, bn = blockIdx.y;
  const int t = threadIdx.x;
  const int tm = t>>4, tn = t&15;
  float acc[16];
  #pragma unroll
  for(int q=0;q<16;q++) acc[q]=0.f;

  const int ml = t>>2;          // 0..63
  const int kq = (t&3)*4;       // 0,4,8,12

  for(int k0=0;k0<K;k0+=16){
    {
      float4 av = *(const float4*)&A[(size_t)(bm*64+ml)*K + k0 + kq];
      As[kq+0][ml]=av.x; As[kq+1][ml]=av.y; As[kq+2][ml]=av.z; As[kq+3][ml]=av.w;
    }
    if(!BKMAJOR){
      float4 bv = *(const float4*)&B[(size_t)(bn*64+ml)*K + k0 + kq];
      Bs[kq+0][ml]=bv.x; Bs[kq+1][ml]=bv.y; Bs[kq+2][ml]=bv.z; Bs[kq+3][ml]=bv.w;
    } else {
      int kl = t>>4;
      int nq = (t&15)*4;
      float4 bv = *(const float4*)&B[(size_t)(k0+kl)*N + bn*64 + nq];
      *(float4*)&Bs[kl][nq] = bv;
    }
    __syncthreads();
    #pragma unroll
    for(int k=0;k<16;k++){
      float4 a4 = *(const float4*)&As[k][tm<<2];
      float4 b4 = *(const float4*)&Bs[k][tn<<2];
      float av[4] = {a4.x,a4.y,a4.z,a4.w};
      float bv[4] = {b4.x,b4.y,b4.z,b4.w};
      #pragma unroll
      for(int mi=0;mi<4;mi++)
        #pragma unroll
        for(int ni=0;ni<4;ni++)
          acc[mi*4+ni] = fmaf(av[mi], bv[ni], acc[mi*4+ni]);
    }
    __syncthreads();
  }
  #pragma unroll
  for(int mi=0;mi<4;mi++){
    int gm = (bm<<6)+(tm<<2)+mi;
    size_t orow = KEYMAP ? ((size_t)(gm>>9)*NP1 + (gm&511)) : (size_t)gm;
    #pragma unroll
    for(int ni=0;ni<4;ni++){
      int gn = (bn<<6)+(tn<<2)+ni;
      float v = acc[mi*4+ni];
      if(bias) v += bias[gn];
      if(RELU) v = fmaxf(v,0.f);
      C[orow*N + gn] = v;
    }
  }
}

// ---------------- key fixups: end-embedding row + zero row 512 ----------------
__global__ void fixup_end(const int* __restrict__ en, const float* __restrict__ end_emb,
                          float* __restrict__ key){
  int b = blockIdx.x, k = threadIdx.x;  // 128 x 128
  int e = en[b];
  key[((size_t)b*NP1 + NENT)*KDIM + k] = 0.f;
  key[((size_t)b*NP1 + e)*KDIM + k] = end_emb[k];
}

// ---------------- gather selected key rows, scaled ----------------
__global__ void gather_kr(const int* __restrict__ su, const float* __restrict__ key,
                          float* __restrict__ KR){
  int idx = blockIdx.x*256 + threadIdx.x;  // 8192*128
  int r = idx >> 7, k = idx & 127;
  int b = r >> 6;
  int s = su[r];
  KR[idx] = key[((size_t)b*NP1 + s)*KDIM + k] * INV_MAX;
}

// ---------------- c0v[f] = q1_w[f,:] . e2_b ----------------
__global__ void c0_kernel(const float* __restrict__ q1_w, const float* __restrict__ e2_b,
                          float* __restrict__ c0v){
  int f = threadIdx.x; // 1 block x 256
  float acc=0.f;
  for(int d=0;d<DIN;d++) acc = fmaf(q1_w[(size_t)f*DIN+d], e2_b[d], acc);
  c0v[f]=acc;
}

// ---------------- gated exclusive prefix over steps; emits relu(U), s1, ng ----------------
__global__ void prefix_kernel(const float* __restrict__ U0, const float* __restrict__ Q1K,
                              const float* __restrict__ c0v, const float* __restrict__ T1,
                              const int* __restrict__ su, const int* __restrict__ en,
                              const int* __restrict__ sun,
                              float* __restrict__ RU, float* __restrict__ s1,
                              float* __restrict__ ngout){
  int b = blockIdx.x, f = threadIdx.x;    // 128 x 256
  float acc = U0[b*DF+f];
  float c0f = c0v[f];
  float s1a = 0.f, ng = 0.f;
  int enb = en[b], sunb = sun[b];
  for(int j=0;j<SSTEP;j++){
    int r = b*SSTEP+j;
    float q = Q1K[(size_t)r*DF+f];
    float tt = T1[(size_t)r*DF+f];
    RU[(size_t)r*DF+f] = fmaxf(acc,0.f);
    int sj = su[r];
    float g = ((j+1)<=sunb && sj!=enb) ? 1.f : 0.f;
    acc = fmaf(g, q + c0f, acc);
    s1a = fmaf(g, tt, s1a);
    ng += g;
  }
  s1[b*DF+f]=s1a;
  if(f==0) ngout[b]=ng;
}

// ---------------- in-place LayerNorm over rows of 512 ----------------
__global__ __launch_bounds__(512)
void ln512(float* __restrict__ G, const float* __restrict__ gam, const float* __restrict__ bet){
  __shared__ float red[32];
  size_t r = blockIdx.x;
  int j = threadIdx.x;
  float v = G[r*G4+j];
  float2 s = block_reduce2(v, v*v, red);
  float mu = s.x*(1.f/512.f);
  float rs = rsqrtf(s.y*(1.f/512.f) - mu*mu + 1e-5f);
  G[r*G4+j] = (v-mu)*rs*gam[j] + bet[j];
}

// ---------------- serial 2-layer LN-LSTM scan (1 block per batch, 512 thr) ----------------
// whh0 + wih1 fp8 in LDS (64KB each); whh1 fp8 in 8 uint4 regs (R5-proven spill-free).
// 6 barriers/step: A(v,v1 matvecs) B(gates0 LN+c) C(u matvec) D(gates1 LN+c).
__global__ __launch_bounds__(512)
__attribute__((amdgpu_waves_per_eu(2,2)))
void lstm_serial(const float* __restrict__ wih, const float* __restrict__ whh,
                 const float* __restrict__ G0,
                 const float* __restrict__ ln_ig, const float* __restrict__ ln_ib,
                 const float* __restrict__ ln_hg, const float* __restrict__ ln_hb,
                 const float* __restrict__ ln_cg, const float* __restrict__ ln_cb,
                 float* __restrict__ H1){
  const int b = blockIdx.x;
  const int j = threadIdx.x;
  __shared__ uint4 W0s8[8][512];       // whh0 fp8  (64 KB)
  __shared__ uint4 W1s8[8][512];       // wih1 fp8  (64 KB)
  __shared__ float h0s[128], h1s[128];
  __shared__ float pvv[512], pv1[512], pvu[512];
  __shared__ float lnA[512], lnB[512], lnC[512], lnD[512], lnE[512], lnF[512];
  __shared__ float red[40];

  // one-time staging: fp8-pack whh0/wih1 -> LDS, whh1 -> regs, LN tables -> LDS
  #pragma unroll
  for(int c=0;c<8;c++){
    const float* s0 = &whh[(size_t)j*KDIM + c*16];
    uint4 p;
    p.x = pk8(*(const float4*)(s0+ 0));
    p.y = pk8(*(const float4*)(s0+ 4));
    p.z = pk8(*(const float4*)(s0+ 8));
    p.w = pk8(*(const float4*)(s0+12));
    W0s8[c][j] = p;
    const float* s1 = &wih[65536 + (size_t)j*KDIM + c*16];
    uint4 q;
    q.x = pk8(*(const float4*)(s1+ 0));
    q.y = pk8(*(const float4*)(s1+ 4));
    q.z = pk8(*(const float4*)(s1+ 8));
    q.w = pk8(*(const float4*)(s1+12));
    W1s8[c][j] = q;
  }
  uint4 w2p[8];
  #pragma unroll
  for(int c=0;c<8;c++){
    const float* s2 = &whh[65536 + (size_t)j*KDIM + c*16];
    w2p[c].x = pk8(*(const float4*)(s2+ 0));
    w2p[c].y = pk8(*(const float4*)(s2+ 4));
    w2p[c].z = pk8(*(const float4*)(s2+ 8));
    w2p[c].w = pk8(*(const float4*)(s2+12));
  }
  lnA[j] = ln_hg[j];     lnB[j] = ln_hb[j];
  lnC[j] = ln_ig[512+j]; lnD[j] = ln_ib[512+j];
  lnE[j] = ln_hg[512+j]; lnF[j] = ln_hb[512+j];

  float cg0=0.f,cb0=0.f,cg1=0.f,cb1=0.f,c0r=0.f,c1r=0.f;
  if(j<128){ cg0=ln_cg[j]; cb0=ln_cb[j]; cg1=ln_cg[128+j]; cb1=ln_cb[128+j]; h0s[j]=0.f; h1s[j]=0.f; }
  __syncthreads();

  const float4* h04 = (const float4*)h0s;
  const float4* h14 = (const float4*)h1s;
  const int w = j>>6;
  float cpre=0.f, og0=0.f, cpre1=0.f, og1=0.f;

  for(int i=0;i<SSTEP;i++){
    // prefetch G0 gate values (only the gate threads need them)
    float g0k[4];
    if(j<128){
      const float* gp = &G0[((size_t)b*SSTEP+i)*G4 + j];
      g0k[0]=gp[0]; g0k[1]=gp[128]; g0k[2]=gp[256]; g0k[3]=gp[384];
    }

    // ---- Phase A: v = whh0@h0_prev (LDS W) ; v1 = whh1@h1_prev (reg W) ----
    float v = 0.f, vb = 0.f;
    #pragma unroll
    for(int c=0;c<8;c++){
      uint4 ww = W0s8[c][j];
      v  = dot4_fp8(ww.x, h04[4*c+0], v );
      vb = dot4_fp8(ww.y, h04[4*c+1], vb);
      v  = dot4_fp8(ww.z, h04[4*c+2], v );
      vb = dot4_fp8(ww.w, h04[4*c+3], vb);
    }
    v += vb;
    float v1 = 0.f, v1b = 0.f;
    #pragma unroll
    for(int c=0;c<8;c++){
      uint4 ww = w2p[c];
      v1  = dot4_fp8(ww.x, h14[4*c+0], v1 );
      v1b = dot4_fp8(ww.y, h14[4*c+1], v1b);
      v1  = dot4_fp8(ww.z, h14[4*c+2], v1 );
      v1b = dot4_fp8(ww.w, h14[4*c+3], v1b);
    }
    v1 += v1b;
    {
      float a=v, bq=v*v, c2=v1, d=v1*v1;
      #pragma unroll
      for(int o=32;o>0;o>>=1){
        a += __shfl_down(a,o,64); bq += __shfl_down(bq,o,64);
        c2 += __shfl_down(c2,o,64); d += __shfl_down(d,o,64);
      }
      if((j&63)==0){ red[w]=a; red[8+w]=bq; red[16+w]=c2; red[24+w]=d; }
    }
    pvv[j]=v; pv1[j]=v1;
    __syncthreads();                                      // bar1

    // ---- Phase B: layer-0 gates (threads 0..127) ----
    if(j<128){
      float S=0.f,S2=0.f;
      #pragma unroll
      for(int q=0;q<8;q++){ S+=red[q]; S2+=red[8+q]; }
      float mu = S*(1.f/512.f);
      float rs = rsqrtf(S2*(1.f/512.f) - mu*mu + 1e-5f);
      float ash[4];
      #pragma unroll
      for(int k=0;k<4;k++){
        int idx = j + 128*k;
        ash[k] = g0k[k] + (pvv[idx]-mu)*rs*lnA[idx] + lnB[idx];
      }
      cpre = sigf(ash[1])*c0r + sigf(ash[0])*tanh_fast(ash[2]);
      og0 = ash[3];
      float sc=cpre, sc2=cpre*cpre;
      #pragma unroll
      for(int o=32;o>0;o>>=1){ sc += __shfl_down(sc,o,64); sc2 += __shfl_down(sc2,o,64); }
      if((j&63)==0){ red[32+w]=sc; red[34+w]=sc2; }
    }
    __syncthreads();                                      // bar2
    if(j<128){
      float Scp = red[32]+red[33], Scp2 = red[34]+red[35];
      float muc = Scp*(1.f/128.f);
      float rsc = rsqrtf(Scp2*(1.f/128.f) - muc*muc + 1e-5f);
      c0r = (cpre-muc)*rsc*cg0 + cb0;
      h0s[j] = sigf(og0)*tanh_fast(c0r);
    }
    __syncthreads();                                      // bar3

    // ---- Phase C: u = wih1 @ h0_new (LDS W) ----
    float u = 0.f, ub = 0.f;
    #pragma unroll
    for(int c=0;c<8;c++){
      uint4 ww = W1s8[c][j];
      u  = dot4_fp8(ww.x, h04[4*c+0], u );
      ub = dot4_fp8(ww.y, h04[4*c+1], ub);
      u  = dot4_fp8(ww.z, h04[4*c+2], u );
      ub = dot4_fp8(ww.w, h04[4*c+3], ub);
    }
    u += ub;
    {
      float a=u, bq=u*u;
      #pragma unroll
      for(int o=32;o>0;o>>=1){ a += __shfl_down(a,o,64); bq += __shfl_down(bq,o,64); }
      if((j&63)==0){ red[w]=a; red[8+w]=bq; }
    }
    pvu[j]=u;
    __syncthreads();                                      // bar4

    // ---- Phase D: layer-1 gates ----
    if(j<128){
      float Su=0.f,Su2=0.f,Sv=0.f,Sv2=0.f;
      #pragma unroll
      for(int q=0;q<8;q++){ Su+=red[q]; Su2+=red[8+q]; Sv+=red[16+q]; Sv2+=red[24+q]; }
      float muu = Su*(1.f/512.f);
      float rsu = rsqrtf(Su2*(1.f/512.f) - muu*muu + 1e-5f);
      float muv = Sv*(1.f/512.f);
      float rsv = rsqrtf(Sv2*(1.f/512.f) - muv*muv + 1e-5f);
      float ash[4];
      #pragma unroll
      for(int k=0;k<4;k++){
        int idx = j + 128*k;
        ash[k] = (pvu[idx]-muu)*rsu*lnC[idx] + lnD[idx]
               + (pv1[idx]-muv)*rsv*lnE[idx] + lnF[idx];
      }
      cpre1 = sigf(ash[1])*c1r + sigf(ash[0])*tanh_fast(ash[2]);
      og1 = ash[3];
      float sc=cpre1, sc2=cpre1*cpre1;
      #pragma unroll
      for(int o=32;o>0;o>>=1){ sc += __shfl_down(sc,o,64); sc2 += __shfl_down(sc2,o,64); }
      if((j&63)==0){ red[32+w]=sc; red[34+w]=sc2; }
    }
    __syncthreads();                                      // bar5
    if(j<128){
      float Scp = red[32]+red[33], Scp2 = red[34]+red[35];
      float muc = Scp*(1.f/128.f);
      float rsc = rsqrtf(Scp2*(1.f/128.f) - muc*muc + 1e-5f);
      c1r = (cpre1-muc)*rsc*cg1 + cb1;
      float h1n = sigf(og1)*tanh_fast(c1r);
      h1s[j] = h1n;
      H1[((size_t)b*SSTEP+i)*HDIM + j] = h1n;
    }
    __syncthreads();                                      // bar6
  }
}

// ---------------- logits: per-batch H1 @ key^T with mask ----------------
__global__ __launch_bounds__(256)
void logits_kernel(const float* __restrict__ key, const float* __restrict__ H1,
                   const int* __restrict__ en, const int* __restrict__ su,
                   float* __restrict__ out){
  const int b = blockIdx.x;
  __shared__ float HsT[128][68];       // [k][i], padded
  __shared__ int firstsel[NP1];
  for(int t=threadIdx.x; t<SSTEP*HDIM; t+=256){
    int i = t>>7, k = t&127;
    HsT[k][i] = H1[(size_t)b*SSTEP*HDIM + t];
  }
  for(int t=threadIdx.x; t<NP1; t+=256) firstsel[t] = 1<<30;
  __syncthreads();
  if(threadIdx.x < SSTEP) atomicMin(&firstsel[su[b*SSTEP+threadIdx.x]], (int)threadIdx.x);
  __syncthreads();
  const int enb = en[b];
  for(int n=threadIdx.x; n<NP1; n+=256){
    if(n > enb){
      for(int i=0;i<SSTEP;i++) out[((size_t)b*SSTEP+i)*NP1 + n] = NEGV;
      continue;
    }
    const float* kr = key + ((size_t)b*NP1 + n)*KDIM;
    const int fs = firstsel[n];
    for(int it=0; it<SSTEP; it+=16){
      float acc[16];
      #pragma unroll
      for(int q=0;q<16;q++) acc[q]=0.f;
      for(int k=0;k<KDIM;k+=4){
        float4 kv = *(const float4*)&kr[k];
        float kvs[4] = {kv.x,kv.y,kv.z,kv.w};
        #pragma unroll
        for(int kk=0;kk<4;kk++){
          #pragma unroll
          for(int qq=0;qq<4;qq++){
            float4 hv = *(const float4*)&HsT[k+kk][it+qq*4];
            acc[qq*4+0] = fmaf(kvs[kk], hv.x, acc[qq*4+0]);
            acc[qq*4+1] = fmaf(kvs[kk], hv.y, acc[qq*4+1]);
            acc[qq*4+2] = fmaf(kvs[kk], hv.z, acc[qq*4+2]);
            acc[qq*4+3] = fmaf(kvs[kk], hv.w, acc[qq*4+3]);
          }
        }
      }
      #pragma unroll
      for(int q=0;q<16;q++){
        int i = it+q;
        bool m = (fs >= i) && !(i==0 && n==enb);
        out[((size_t)b*SSTEP+i)*NP1 + n] = m ? acc[q] : NEGV;
      }
    }
  }
}

// ---------------- final ae + selected_units_num ----------------
__global__ void ae_out_kernel(const float* __restrict__ emb, const float* __restrict__ P,
                              const float* __restrict__ e2_b, const float* __restrict__ ng,
                              const int* __restrict__ sun, float* __restrict__ out){
  const size_t AE_OFF = (size_t)BSZ*SSTEP*NP1;
  const size_t SUN_OFF = AE_OFF + (size_t)BSZ*DIN;
  int idx = blockIdx.x*256+threadIdx.x;   // 131072
  int b = idx>>10, d = idx&1023;
  out[AE_OFF + idx] = emb[idx] + P[idx] + ng[b]*e2_b[d];
  if(idx < BSZ) out[SUN_OFF + idx] = (float)sun[idx];
}

// ---------------- launch ----------------
extern "C" void kernel_launch(void* const* d_in, const int* in_sizes, int n_in,
                              void* d_out, int out_size, void* d_ws, size_t ws_size,
                              hipStream_t stream){
  const float* emb     = (const float*)d_in[0];
  const float* ent     = (const float*)d_in[1];
  const float* key_w   = (const float*)d_in[2];
  const float* key_b   = (const float*)d_in[3];
  const float* q1_w    = (const float*)d_in[4];
  const float* q1_b    = (const float*)d_in[5];
  const float* q2_w    = (const float*)d_in[6];
  const float* q2_b    = (const float*)d_in[7];
  const float* e1_w    = (const float*)d_in[8];
  const float* e1_b    = (const float*)d_in[9];
  const float* e2_w    = (const float*)d_in[10];
  const float* e2_b    = (const float*)d_in[11];
  const float* end_emb = (const float*)d_in[12];
  const float* wih     = (const float*)d_in[13];
  const float* whh     = (const float*)d_in[14];
  const float* ln_ig   = (const float*)d_in[15];
  const float* ln_ib   = (const float*)d_in[16];
  const float* ln_hg   = (const float*)d_in[17];
  const float* ln_hb   = (const float*)d_in[18];
  const float* ln_cg   = (const float*)d_in[19];
  const float* ln_cb   = (const float*)d_in[20];
  const int* en  = (const int*)d_in[21];
  const int* su  = (const int*)d_in[22];
  const int* sun = (const int*)d_in[23];
  float* out = (float*)d_out;
  float* ws  = (float*)d_ws;

  // workspace layout (float units)
  const size_t o_key = 0;                       // 128*513*128 = 8,404,992
  const size_t o_KR  = o_key + 8404992;         // 1,048,576
  const size_t o_T1  = o_KR  + 1048576;         // 2,097,152
  const size_t o_q1e = o_T1  + 2097152;         // 65,536
  const size_t o_c0  = o_q1e + 65536;           // 1,024 (256 used)
  const size_t o_U0  = o_c0  + 1024;            // 32,768
  const size_t o_Q1K = o_U0  + 32768;           // 2,097,152
  const size_t o_RU  = o_Q1K + 2097152;         // 2,097,152
  const size_t o_X   = o_RU  + 2097152;         // 1,048,576
  const size_t o_G0  = o_X   + 1048576;         // 4,194,304
  const size_t o_s1  = o_G0  + 4194304;         // 32,768
  const size_t o_ng  = o_s1  + 32768;           // 1,024 (128 used)
  const size_t o_H1  = o_ng  + 1024;            // 1,048,576
  const size_t o_P   = o_H1  + 1048576;         // 131,072

  // 1) key = ent_emb @ key_w^T + key_b  (rows mapped into 513-stride layout)
  gemm_kernel<false,false,true><<<dim3(1024,2),256,0,stream>>>(ent, key_w, key_b, ws+o_key, 65536,128,256);
  // 2) end-embedding row + zero row 512
  fixup_end<<<128,128,0,stream>>>(en, end_emb, ws+o_key);
  // 3) gather selected rows / 512
  gather_kr<<<4096,256,0,stream>>>(su, ws+o_key, ws+o_KR);
  // 4) T1 = relu(KR @ e1_w^T + e1_b)
  gemm_kernel<false,true,false><<<dim3(128,4),256,0,stream>>>(ws+o_KR, e1_w, e1_b, ws+o_T1, 8192,256,128);
  // 5) q1e = q1_w @ e2_w   (fused 256x256 weight)
  gemm_kernel<true,false,false><<<dim3(4,4),256,0,stream>>>(q1_w, e2_w, nullptr, ws+o_q1e, 256,256,1024);
  // 6) c0 = q1_w @ e2_b
  c0_kernel<<<1,256,0,stream>>>(q1_w, e2_b, ws+o_c0);
  // 7) U0 = emb @ q1_w^T + q1_b
  gemm_kernel<false,false,false><<<dim3(2,4),256,0,stream>>>(emb, q1_w, q1_b, ws+o_U0, 128,256,1024);
  // 8) Q1K = T1 @ q1e^T
  gemm_kernel<false,false,false><<<dim3(128,4),256,0,stream>>>(ws+o_T1, ws+o_q1e, nullptr, ws+o_Q1K, 8192,256,256);
  // 9) gated exclusive prefix -> relu(U), s1, ng
  prefix_kernel<<<128,256,0,stream>>>(ws+o_U0, ws+o_Q1K, ws+o_c0, ws+o_T1, su, en, sun,
                                      ws+o_RU, ws+o_s1, ws+o_ng);
  // 10) X = RU @ q2_w^T + q2_b
  gemm_kernel<false,false,false><<<dim3(128,2),256,0,stream>>>(ws+o_RU, q2_w, q2_b, ws+o_X, 8192,128,256);
  // 11) G0 = X @ wih0^T ; then in-place LN with ln_ig0/ln_ib0
  gemm_kernel<false,false,false><<<dim3(128,8),256,0,stream>>>(ws+o_X, wih, nullptr, ws+o_G0, 8192,512,128);
  ln512<<<8192,512,0,stream>>>(ws+o_G0, ln_ig, ln_ib);
  // 12) serial LN-LSTM scan -> H1 (whh0+wih1 fp8 LDS, whh1 fp8 regs; 6 barriers/step)
  lstm_serial<<<128,512,0,stream>>>(wih, whh, ws+o_G0,
                                    ln_ig, ln_ib, ln_hg, ln_hb, ln_cg, ln_cb, ws+o_H1);
  // 13) logits (masked) directly into d_out
  logits_kernel<<<128,256,0,stream>>>(ws+o_key, ws+o_H1, en, su, out);
  // 14) P = s1 @ e2_w^T ; ae = emb + P + ng*e2_b ; sun passthrough
  gemm_kernel<false,false,false><<<dim3(2,16),256,0,stream>>>(ws+o_s1, e2_w, nullptr, ws+o_P, 128,1024,256);
  ae_out_kernel<<<512,256,0,stream>>>(emb, ws+o_P, e2_b, ws+o_ng, sun, out);
}

// Round 8
// 753.500 us; speedup vs baseline: 2.2289x; 1.0146x over previous
//
#include <hip/hip_runtime.h>
#include <hip/hip_bf16.h>
#include <math.h>

#define BSZ   128
#define NENT  512
#define NP1   513
#define DENT  256
#define KDIM  128
#define DIN   1024
#define DF    256
#define HDIM  128
#define SSTEP 64
#define G4    512
#define NEGV  (-1e9f)
#define INV_MAX (1.0f/512.0f)

typedef float v2f __attribute__((ext_vector_type(2)));

// ---------------- helpers ----------------
__device__ inline float sigf(float x){ return 1.f/(1.f+__expf(-x)); }
__device__ inline float tanh_fast(float x){ float e=__expf(2.f*x); return 1.f - 2.f/(e+1.f); }

// pack 4 floats -> 4 fp8 e4m3 in one dword
__device__ inline unsigned pk8(float4 f){
  int r = 0;
  r = __builtin_amdgcn_cvt_pk_fp8_f32(f.x, f.y, r, false);
  r = __builtin_amdgcn_cvt_pk_fp8_f32(f.z, f.w, r, true);
  return (unsigned)r;
}
// acc += dot(4 fp8 cols in w, h)
__device__ inline float dot4_fp8(unsigned w, float4 h, float acc){
  v2f p = __builtin_amdgcn_cvt_pk_f32_fp8((int)w, false);
  acc = fmaf(p.x, h.x, acc); acc = fmaf(p.y, h.y, acc);
  p = __builtin_amdgcn_cvt_pk_f32_fp8((int)w, true);
  acc = fmaf(p.x, h.z, acc); acc = fmaf(p.y, h.w, acc);
  return acc;
}

// block = 512 threads (8 waves). Returns sums over the block to ALL threads.
__device__ inline float2 block_reduce2(float x, float y, float* red){
  #pragma unroll
  for(int o=32;o>0;o>>=1){ x += __shfl_down(x,o,64); y += __shfl_down(y,o,64); }
  int w = threadIdx.x>>6;
  __syncthreads();
  if((threadIdx.x&63)==0){ red[w]=x; red[8+w]=y; }
  __syncthreads();
  float sx=0.f, sy=0.f;
  #pragma unroll
  for(int q=0;q<8;q++){ sx+=red[q]; sy+=red[8+q]; }
  return make_float2(sx,sy);
}

// ---------------- generic tiled GEMM: C[M,N] = act(A[M,K] @ B^T + bias) ----------------
template<bool BKMAJOR, bool RELU, bool KEYMAP>
__global__ __launch_bounds__(256)
void gemm_kernel(const float* __restrict__ A, const float* __restrict__ B,
                 const float* __restrict__ bias, float* __restrict__ C,
                 int M, int N, int K){
  __shared__ float As[16][64];
  __shared__ float Bs[16][64];
  const int bm = blockIdx.x, bn = blockIdx.y;
  const int t = threadIdx.x;
  const int tm = t>>4, tn = t&15;
  float acc[16];
  #pragma unroll
  for(int q=0;q<16;q++) acc[q]=0.f;

  const int ml = t>>2;          // 0..63
  const int kq = (t&3)*4;       // 0,4,8,12

  for(int k0=0;k0<K;k0+=16){
    {
      float4 av = *(const float4*)&A[(size_t)(bm*64+ml)*K + k0 + kq];
      As[kq+0][ml]=av.x; As[kq+1][ml]=av.y; As[kq+2][ml]=av.z; As[kq+3][ml]=av.w;
    }
    if(!BKMAJOR){
      float4 bv = *(const float4*)&B[(size_t)(bn*64+ml)*K + k0 + kq];
      Bs[kq+0][ml]=bv.x; Bs[kq+1][ml]=bv.y; Bs[kq+2][ml]=bv.z; Bs[kq+3][ml]=bv.w;
    } else {
      int kl = t>>4;
      int nq = (t&15)*4;
      float4 bv = *(const float4*)&B[(size_t)(k0+kl)*N + bn*64 + nq];
      *(float4*)&Bs[kl][nq] = bv;
    }
    __syncthreads();
    #pragma unroll
    for(int k=0;k<16;k++){
      float4 a4 = *(const float4*)&As[k][tm<<2];
      float4 b4 = *(const float4*)&Bs[k][tn<<2];
      float av[4] = {a4.x,a4.y,a4.z,a4.w};
      float bv[4] = {b4.x,b4.y,b4.z,b4.w};
      #pragma unroll
      for(int mi=0;mi<4;mi++)
        #pragma unroll
        for(int ni=0;ni<4;ni++)
          acc[mi*4+ni] = fmaf(av[mi], bv[ni], acc[mi*4+ni]);
    }
    __syncthreads();
  }
  #pragma unroll
  for(int mi=0;mi<4;mi++){
    int gm = (bm<<6)+(tm<<2)+mi;
    size_t orow = KEYMAP ? ((size_t)(gm>>9)*NP1 + (gm&511)) : (size_t)gm;
    #pragma unroll
    for(int ni=0;ni<4;ni++){
      int gn = (bn<<6)+(tn<<2)+ni;
      float v = acc[mi*4+ni];
      if(bias) v += bias[gn];
      if(RELU) v = fmaxf(v,0.f);
      C[orow*N + gn] = v;
    }
  }
}

// ---------------- key fixups: end-embedding row + zero row 512 ----------------
__global__ void fixup_end(const int* __restrict__ en, const float* __restrict__ end_emb,
                          float* __restrict__ key){
  int b = blockIdx.x, k = threadIdx.x;  // 128 x 128
  int e = en[b];
  key[((size_t)b*NP1 + NENT)*KDIM + k] = 0.f;
  key[((size_t)b*NP1 + e)*KDIM + k] = end_emb[k];
}

// ---------------- gather selected key rows, scaled ----------------
__global__ void gather_kr(const int* __restrict__ su, const float* __restrict__ key,
                          float* __restrict__ KR){
  int idx = blockIdx.x*256 + threadIdx.x;  // 8192*128
  int r = idx >> 7, k = idx & 127;
  int b = r >> 6;
  int s = su[r];
  KR[idx] = key[((size_t)b*NP1 + s)*KDIM + k] * INV_MAX;
}

// ---------------- c0v[f] = q1_w[f,:] . e2_b ----------------
__global__ void c0_kernel(const float* __restrict__ q1_w, const float* __restrict__ e2_b,
                          float* __restrict__ c0v){
  int f = threadIdx.x; // 1 block x 256
  float acc=0.f;
  for(int d=0;d<DIN;d+=4){
    float4 a = *(const float4*)&q1_w[(size_t)f*DIN+d];
    float4 e = *(const float4*)&e2_b[d];
    acc = fmaf(a.x,e.x,acc); acc = fmaf(a.y,e.y,acc);
    acc = fmaf(a.z,e.z,acc); acc = fmaf(a.w,e.w,acc);
  }
  c0v[f]=acc;
}

// ---------------- gated exclusive prefix over steps; emits relu(U), s1, ng ----------------
__global__ void prefix_kernel(const float* __restrict__ U0, const float* __restrict__ Q1K,
                              const float* __restrict__ c0v, const float* __restrict__ T1,
                              const int* __restrict__ su, const int* __restrict__ en,
                              const int* __restrict__ sun,
                              float* __restrict__ RU, float* __restrict__ s1,
                              float* __restrict__ ngout){
  int b = blockIdx.x, f = threadIdx.x;    // 128 x 256
  float acc = U0[b*DF+f];
  float c0f = c0v[f];
  float s1a = 0.f, ng = 0.f;
  int enb = en[b], sunb = sun[b];
  for(int j=0;j<SSTEP;j++){
    int r = b*SSTEP+j;
    float q = Q1K[(size_t)r*DF+f];
    float tt = T1[(size_t)r*DF+f];
    RU[(size_t)r*DF+f] = fmaxf(acc,0.f);
    int sj = su[r];
    float g = ((j+1)<=sunb && sj!=enb) ? 1.f : 0.f;
    acc = fmaf(g, q + c0f, acc);
    s1a = fmaf(g, tt, s1a);
    ng += g;
  }
  s1[b*DF+f]=s1a;
  if(f==0) ngout[b]=ng;
}

// ---------------- in-place LayerNorm over rows of 512 ----------------
__global__ __launch_bounds__(512)
void ln512(float* __restrict__ G, const float* __restrict__ gam, const float* __restrict__ bet){
  __shared__ float red[32];
  size_t r = blockIdx.x;
  int j = threadIdx.x;
  float v = G[r*G4+j];
  float2 s = block_reduce2(v, v*v, red);
  float mu = s.x*(1.f/512.f);
  float rs = rsqrtf(s.y*(1.f/512.f) - mu*mu + 1e-5f);
  G[r*G4+j] = (v-mu)*rs*gam[j] + bet[j];
}

// ---------------- serial 2-layer LN-LSTM scan (1 block per batch, 512 thr) ----------------
// whh0 + wih1 fp8 in LDS; whh1 fp8 in 8 uint4 regs. 4 barriers/step; gate phases on
// ONE wave (threads 0..63, 2 cells each) so the c-LN reduce is wave-internal shfl_xor.
__global__ __launch_bounds__(512)
__attribute__((amdgpu_waves_per_eu(2,2)))
void lstm_serial(const float* __restrict__ wih, const float* __restrict__ whh,
                 const float* __restrict__ G0,
                 const float* __restrict__ ln_ig, const float* __restrict__ ln_ib,
                 const float* __restrict__ ln_hg, const float* __restrict__ ln_hb,
                 const float* __restrict__ ln_cg, const float* __restrict__ ln_cb,
                 float* __restrict__ H1){
  const int b = blockIdx.x;
  const int j = threadIdx.x;
  __shared__ uint4 W0s8[8][512];       // whh0 fp8  (64 KB)
  __shared__ uint4 W1s8[8][512];       // wih1 fp8  (64 KB)
  __shared__ float h0s[128], h1s[128];
  __shared__ float pvv[512], pv1[512];
  __shared__ float lnA[512], lnB[512], lnC[512], lnD[512], lnE[512], lnF[512];
  __shared__ float red[32];

  // one-time staging: fp8-pack whh0/wih1 -> LDS, whh1 -> regs, LN tables -> LDS
  #pragma unroll
  for(int c=0;c<8;c++){
    const float* s0 = &whh[(size_t)j*KDIM + c*16];
    uint4 p;
    p.x = pk8(*(const float4*)(s0+ 0));
    p.y = pk8(*(const float4*)(s0+ 4));
    p.z = pk8(*(const float4*)(s0+ 8));
    p.w = pk8(*(const float4*)(s0+12));
    W0s8[c][j] = p;
    const float* s1 = &wih[65536 + (size_t)j*KDIM + c*16];
    uint4 q;
    q.x = pk8(*(const float4*)(s1+ 0));
    q.y = pk8(*(const float4*)(s1+ 4));
    q.z = pk8(*(const float4*)(s1+ 8));
    q.w = pk8(*(const float4*)(s1+12));
    W1s8[c][j] = q;
  }
  uint4 w2p[8];
  #pragma unroll
  for(int c=0;c<8;c++){
    const float* s2 = &whh[65536 + (size_t)j*KDIM + c*16];
    w2p[c].x = pk8(*(const float4*)(s2+ 0));
    w2p[c].y = pk8(*(const float4*)(s2+ 4));
    w2p[c].z = pk8(*(const float4*)(s2+ 8));
    w2p[c].w = pk8(*(const float4*)(s2+12));
  }
  lnA[j] = ln_hg[j];     lnB[j] = ln_hb[j];
  lnC[j] = ln_ig[512+j]; lnD[j] = ln_ib[512+j];
  lnE[j] = ln_hg[512+j]; lnF[j] = ln_hb[512+j];

  // gate-wave per-thread state (cells j and j+64), threads 0..63
  float cg0A=0.f,cb0A=0.f,cg0B=0.f,cb0B=0.f;
  float cg1A=0.f,cb1A=0.f,cg1B=0.f,cb1B=0.f;
  float c0rA=0.f,c0rB=0.f,c1rA=0.f,c1rB=0.f;
  if(j<64){
    cg0A=ln_cg[j];      cb0A=ln_cb[j];
    cg0B=ln_cg[j+64];   cb0B=ln_cb[j+64];
    cg1A=ln_cg[128+j];    cb1A=ln_cb[128+j];
    cg1B=ln_cg[128+j+64]; cb1B=ln_cb[128+j+64];
  }
  if(j<128){ h0s[j]=0.f; h1s[j]=0.f; }
  __syncthreads();

  const float4* h04 = (const float4*)h0s;
  const float4* h14 = (const float4*)h1s;
  const int w = j>>6;

  for(int i=0;i<SSTEP;i++){
    // gate-wave prefetch of this step's precomputed layer-0 input gates
    float g0a[4], g0b[4];
    if(j<64){
      const float* gp = &G0[((size_t)b*SSTEP+i)*G4];
      #pragma unroll
      for(int k=0;k<4;k++){ g0a[k]=gp[j+128*k]; g0b[k]=gp[j+64+128*k]; }
    }

    // ---- Phase A: v = whh0@h0_prev (LDS W) ; v1 = whh1@h1_prev (reg W) ----
    float v = 0.f, vb = 0.f;
    #pragma unroll
    for(int c=0;c<8;c++){
      uint4 ww = W0s8[c][j];
      v  = dot4_fp8(ww.x, h04[4*c+0], v );
      vb = dot4_fp8(ww.y, h04[4*c+1], vb);
      v  = dot4_fp8(ww.z, h04[4*c+2], v );
      vb = dot4_fp8(ww.w, h04[4*c+3], vb);
    }
    v += vb;
    float v1 = 0.f, v1b = 0.f;
    #pragma unroll
    for(int c=0;c<8;c++){
      uint4 ww = w2p[c];
      v1  = dot4_fp8(ww.x, h14[4*c+0], v1 );
      v1b = dot4_fp8(ww.y, h14[4*c+1], v1b);
      v1  = dot4_fp8(ww.z, h14[4*c+2], v1 );
      v1b = dot4_fp8(ww.w, h14[4*c+3], v1b);
    }
    v1 += v1b;
    {
      float a=v, bq=v*v, c2=v1, d=v1*v1;
      #pragma unroll
      for(int o=32;o>0;o>>=1){
        a += __shfl_down(a,o,64); bq += __shfl_down(bq,o,64);
        c2 += __shfl_down(c2,o,64); d += __shfl_down(d,o,64);
      }
      if((j&63)==0){ red[w]=a; red[8+w]=bq; red[16+w]=c2; red[24+w]=d; }
    }
    pvv[j]=v; pv1[j]=v1;
    __syncthreads();                                      // bar1

    // ---- Phase B: layer-0 gates on ONE wave (cells j, j+64) ----
    if(j<64){
      float S=0.f,S2=0.f;
      #pragma unroll
      for(int q=0;q<8;q++){ S+=red[q]; S2+=red[8+q]; }
      float mu = S*(1.f/512.f);
      float rs = rsqrtf(S2*(1.f/512.f) - mu*mu + 1e-5f);
      float ashA[4], ashB[4];
      #pragma unroll
      for(int k=0;k<4;k++){
        int ia = j + 128*k, ib = j + 64 + 128*k;
        ashA[k] = g0a[k] + (pvv[ia]-mu)*rs*lnA[ia] + lnB[ia];
        ashB[k] = g0b[k] + (pvv[ib]-mu)*rs*lnA[ib] + lnB[ib];
      }
      float cpA = sigf(ashA[1])*c0rA + sigf(ashA[0])*tanh_fast(ashA[2]);
      float cpB = sigf(ashB[1])*c0rB + sigf(ashB[0])*tanh_fast(ashB[2]);
      float s = cpA+cpB, s2 = cpA*cpA+cpB*cpB;
      #pragma unroll
      for(int o=32;o>0;o>>=1){ s += __shfl_xor(s,o,64); s2 += __shfl_xor(s2,o,64); }
      float muc = s*(1.f/128.f);
      float rsc = rsqrtf(s2*(1.f/128.f) - muc*muc + 1e-5f);
      c0rA = (cpA-muc)*rsc*cg0A + cb0A;
      c0rB = (cpB-muc)*rsc*cg0B + cb0B;
      h0s[j]    = sigf(ashA[3])*tanh_fast(c0rA);
      h0s[j+64] = sigf(ashB[3])*tanh_fast(c0rB);
    }
    __syncthreads();                                      // bar2

    // ---- Phase C: u = wih1 @ h0_new (LDS W) ----
    float u = 0.f, ub = 0.f;
    #pragma unroll
    for(int c=0;c<8;c++){
      uint4 ww = W1s8[c][j];
      u  = dot4_fp8(ww.x, h04[4*c+0], u );
      ub = dot4_fp8(ww.y, h04[4*c+1], ub);
      u  = dot4_fp8(ww.z, h04[4*c+2], u );
      ub = dot4_fp8(ww.w, h04[4*c+3], ub);
    }
    u += ub;
    {
      float a=u, bq=u*u;
      #pragma unroll
      for(int o=32;o>0;o>>=1){ a += __shfl_down(a,o,64); bq += __shfl_down(bq,o,64); }
      if((j&63)==0){ red[w]=a; red[8+w]=bq; }
    }
    pvv[j]=u;                                             // reuse pvv for u
    __syncthreads();                                      // bar3

    // ---- Phase D: layer-1 gates on ONE wave ----
    if(j<64){
      float Su=0.f,Su2=0.f,Sv=0.f,Sv2=0.f;
      #pragma unroll
      for(int q=0;q<8;q++){ Su+=red[q]; Su2+=red[8+q]; Sv+=red[16+q]; Sv2+=red[24+q]; }
      float muu = Su*(1.f/512.f);
      float rsu = rsqrtf(Su2*(1.f/512.f) - muu*muu + 1e-5f);
      float muv = Sv*(1.f/512.f);
      float rsv = rsqrtf(Sv2*(1.f/512.f) - muv*muv + 1e-5f);
      float ashA[4], ashB[4];
      #pragma unroll
      for(int k=0;k<4;k++){
        int ia = j + 128*k, ib = j + 64 + 128*k;
        ashA[k] = (pvv[ia]-muu)*rsu*lnC[ia] + lnD[ia]
                + (pv1[ia]-muv)*rsv*lnE[ia] + lnF[ia];
        ashB[k] = (pvv[ib]-muu)*rsu*lnC[ib] + lnD[ib]
                + (pv1[ib]-muv)*rsv*lnE[ib] + lnF[ib];
      }
      float cpA = sigf(ashA[1])*c1rA + sigf(ashA[0])*tanh_fast(ashA[2]);
      float cpB = sigf(ashB[1])*c1rB + sigf(ashB[0])*tanh_fast(ashB[2]);
      float s = cpA+cpB, s2 = cpA*cpA+cpB*cpB;
      #pragma unroll
      for(int o=32;o>0;o>>=1){ s += __shfl_xor(s,o,64); s2 += __shfl_xor(s2,o,64); }
      float muc = s*(1.f/128.f);
      float rsc = rsqrtf(s2*(1.f/128.f) - muc*muc + 1e-5f);
      c1rA = (cpA-muc)*rsc*cg1A + cb1A;
      c1rB = (cpB-muc)*rsc*cg1B + cb1B;
      float hA = sigf(ashA[3])*tanh_fast(c1rA);
      float hB = sigf(ashB[3])*tanh_fast(c1rB);
      h1s[j]    = hA;
      h1s[j+64] = hB;
      H1[((size_t)b*SSTEP+i)*HDIM + j]      = hA;
      H1[((size_t)b*SSTEP+i)*HDIM + j + 64] = hB;
    }
    __syncthreads();                                      // bar4
  }
}

// ---------------- logits: per-batch H1 @ key^T with mask ----------------
__global__ __launch_bounds__(256)
void logits_kernel(const float* __restrict__ key, const float* __restrict__ H1,
                   const int* __restrict__ en, const int* __restrict__ su,
                   float* __restrict__ out){
  const int b = blockIdx.x;
  __shared__ float HsT[128][68];       // [k][i], padded
  __shared__ int firstsel[NP1];
  for(int t=threadIdx.x; t<SSTEP*HDIM; t+=256){
    int i = t>>7, k = t&127;
    HsT[k][i] = H1[(size_t)b*SSTEP*HDIM + t];
  }
  for(int t=threadIdx.x; t<NP1; t+=256) firstsel[t] = 1<<30;
  __syncthreads();
  if(threadIdx.x < SSTEP) atomicMin(&firstsel[su[b*SSTEP+threadIdx.x]], (int)threadIdx.x);
  __syncthreads();
  const int enb = en[b];
  for(int n=threadIdx.x; n<NP1; n+=256){
    if(n > enb){
      for(int i=0;i<SSTEP;i++) out[((size_t)b*SSTEP+i)*NP1 + n] = NEGV;
      continue;
    }
    const float* kr = key + ((size_t)b*NP1 + n)*KDIM;
    const int fs = firstsel[n];
    for(int it=0; it<SSTEP; it+=16){
      float acc[16];
      #pragma unroll
      for(int q=0;q<16;q++) acc[q]=0.f;
      for(int k=0;k<KDIM;k+=4){
        float4 kv = *(const float4*)&kr[k];
        float kvs[4] = {kv.x,kv.y,kv.z,kv.w};
        #pragma unroll
        for(int kk=0;kk<4;kk++){
          #pragma unroll
          for(int qq=0;qq<4;qq++){
            float4 hv = *(const float4*)&HsT[k+kk][it+qq*4];
            acc[qq*4+0] = fmaf(kvs[kk], hv.x, acc[qq*4+0]);
            acc[qq*4+1] = fmaf(kvs[kk], hv.y, acc[qq*4+1]);
            acc[qq*4+2] = fmaf(kvs[kk], hv.z, acc[qq*4+2]);
            acc[qq*4+3] = fmaf(kvs[kk], hv.w, acc[qq*4+3]);
          }
        }
      }
      #pragma unroll
      for(int q=0;q<16;q++){
        int i = it+q;
        bool m = (fs >= i) && !(i==0 && n==enb);
        out[((size_t)b*SSTEP+i)*NP1 + n] = m ? acc[q] : NEGV;
      }
    }
  }
}

// ---------------- final ae + selected_units_num ----------------
__global__ void ae_out_kernel(const float* __restrict__ emb, const float* __restrict__ P,
                              const float* __restrict__ e2_b, const float* __restrict__ ng,
                              const int* __restrict__ sun, float* __restrict__ out){
  const size_t AE_OFF = (size_t)BSZ*SSTEP*NP1;
  const size_t SUN_OFF = AE_OFF + (size_t)BSZ*DIN;
  int idx = blockIdx.x*256+threadIdx.x;   // 131072
  int b = idx>>10, d = idx&1023;
  out[AE_OFF + idx] = emb[idx] + P[idx] + ng[b]*e2_b[d];
  if(idx < BSZ) out[SUN_OFF + idx] = (float)sun[idx];
}

// ---------------- launch ----------------
extern "C" void kernel_launch(void* const* d_in, const int* in_sizes, int n_in,
                              void* d_out, int out_size, void* d_ws, size_t ws_size,
                              hipStream_t stream){
  const float* emb     = (const float*)d_in[0];
  const float* ent     = (const float*)d_in[1];
  const float* key_w   = (const float*)d_in[2];
  const float* key_b   = (const float*)d_in[3];
  const float* q1_w    = (const float*)d_in[4];
  const float* q1_b    = (const float*)d_in[5];
  const float* q2_w    = (const float*)d_in[6];
  const float* q2_b    = (const float*)d_in[7];
  const float* e1_w    = (const float*)d_in[8];
  const float* e1_b    = (const float*)d_in[9];
  const float* e2_w    = (const float*)d_in[10];
  const float* e2_b    = (const float*)d_in[11];
  const float* end_emb = (const float*)d_in[12];
  const float* wih     = (const float*)d_in[13];
  const float* whh     = (const float*)d_in[14];
  const float* ln_ig   = (const float*)d_in[15];
  const float* ln_ib   = (const float*)d_in[16];
  const float* ln_hg   = (const float*)d_in[17];
  const float* ln_hb   = (const float*)d_in[18];
  const float* ln_cg   = (const float*)d_in[19];
  const float* ln_cb   = (const float*)d_in[20];
  const int* en  = (const int*)d_in[21];
  const int* su  = (const int*)d_in[22];
  const int* sun = (const int*)d_in[23];
  float* out = (float*)d_out;
  float* ws  = (float*)d_ws;

  // workspace layout (float units)
  const size_t o_key = 0;                       // 128*513*128 = 8,404,992
  const size_t o_KR  = o_key + 8404992;         // 1,048,576
  const size_t o_T1  = o_KR  + 1048576;         // 2,097,152
  const size_t o_q1e = o_T1  + 2097152;         // 65,536
  const size_t o_c0  = o_q1e + 65536;           // 1,024 (256 used)
  const size_t o_U0  = o_c0  + 1024;            // 32,768
  const size_t o_Q1K = o_U0  + 32768;           // 2,097,152
  const size_t o_RU  = o_Q1K + 2097152;         // 2,097,152
  const size_t o_X   = o_RU  + 2097152;         // 1,048,576
  const size_t o_G0  = o_X   + 1048576;         // 4,194,304
  const size_t o_s1  = o_G0  + 4194304;         // 32,768
  const size_t o_ng  = o_s1  + 32768;           // 1,024 (128 used)
  const size_t o_H1  = o_ng  + 1024;            // 1,048,576
  const size_t o_P   = o_H1  + 1048576;         // 131,072

  // 1) key = ent_emb @ key_w^T + key_b  (rows mapped into 513-stride layout)
  gemm_kernel<false,false,true><<<dim3(1024,2),256,0,stream>>>(ent, key_w, key_b, ws+o_key, 65536,128,256);
  // 2) end-embedding row + zero row 512
  fixup_end<<<128,128,0,stream>>>(en, end_emb, ws+o_key);
  // 3) gather selected rows / 512
  gather_kr<<<4096,256,0,stream>>>(su, ws+o_key, ws+o_KR);
  // 4) T1 = relu(KR @ e1_w^T + e1_b)
  gemm_kernel<false,true,false><<<dim3(128,4),256,0,stream>>>(ws+o_KR, e1_w, e1_b, ws+o_T1, 8192,256,128);
  // 5) q1e = q1_w @ e2_w   (fused 256x256 weight)
  gemm_kernel<true,false,false><<<dim3(4,4),256,0,stream>>>(q1_w, e2_w, nullptr, ws+o_q1e, 256,256,1024);
  // 6) c0 = q1_w @ e2_b
  c0_kernel<<<1,256,0,stream>>>(q1_w, e2_b, ws+o_c0);
  // 7) U0 = emb @ q1_w^T + q1_b
  gemm_kernel<false,false,false><<<dim3(2,4),256,0,stream>>>(emb, q1_w, q1_b, ws+o_U0, 128,256,1024);
  // 8) Q1K = T1 @ q1e^T
  gemm_kernel<false,false,false><<<dim3(128,4),256,0,stream>>>(ws+o_T1, ws+o_q1e, nullptr, ws+o_Q1K, 8192,256,256);
  // 9) gated exclusive prefix -> relu(U), s1, ng
  prefix_kernel<<<128,256,0,stream>>>(ws+o_U0, ws+o_Q1K, ws+o_c0, ws+o_T1, su, en, sun,
                                      ws+o_RU, ws+o_s1, ws+o_ng);
  // 10) X = RU @ q2_w^T + q2_b
  gemm_kernel<false,false,false><<<dim3(128,2),256,0,stream>>>(ws+o_RU, q2_w, q2_b, ws+o_X, 8192,128,256);
  // 11) G0 = X @ wih0^T ; then in-place LN with ln_ig0/ln_ib0
  gemm_kernel<false,false,false><<<dim3(128,8),256,0,stream>>>(ws+o_X, wih, nullptr, ws+o_G0, 8192,512,128);
  ln512<<<8192,512,0,stream>>>(ws+o_G0, ln_ig, ln_ib);
  // 12) serial LN-LSTM scan -> H1 (4 barriers/step, 1-wave gate phases)
  lstm_serial<<<128,512,0,stream>>>(wih, whh, ws+o_G0,
                                    ln_ig, ln_ib, ln_hg, ln_hb, ln_cg, ln_cb, ws+o_H1);
  // 13) logits (masked) directly into d_out
  logits_kernel<<<128,256,0,stream>>>(ws+o_key, ws+o_H1, en, su, out);
  // 14) P = s1 @ e2_w^T ; ae = emb + P + ng*e2_b ; sun passthrough
  gemm_kernel<false,false,false><<<dim3(2,16),256,0,stream>>>(ws+o_s1, e2_w, nullptr, ws+o_P, 128,1024,256);
  ae_out_kernel<<<512,256,0,stream>>>(emb, ws+o_P, e2_b, ws+o_ng, sun, out);
}

// Round 9
// 704.178 us; speedup vs baseline: 2.3851x; 1.0700x over previous
//
#include <hip/hip_runtime.h>
#include <hip/hip_bf16.h>
#include <math.h>

#define BSZ   128
#define NENT  512
#define NP1   513
#define DENT  256
#define KDIM  128
#define DIN   1024
#define DF    256
#define HDIM  128
#define SSTEP 64
#define G4    512
#define NEGV  (-1e9f)
#define INV_MAX (1.0f/512.0f)

typedef float v2f __attribute__((ext_vector_type(2)));

// ---------------- helpers ----------------
__device__ inline float sigf(float x){ return 1.f/(1.f+__expf(-x)); }
__device__ inline float tanh_fast(float x){ float e=__expf(2.f*x); return 1.f - 2.f/(e+1.f); }

// DPP wave-64 sum: row_shr 1/2/4/8 + row_bcast15 + row_bcast31; total in lane 63.
__device__ inline float wave_sum_partial(float x){
  x += __int_as_float(__builtin_amdgcn_update_dpp(0, __float_as_int(x), 0x111, 0xf, 0xf, true));
  x += __int_as_float(__builtin_amdgcn_update_dpp(0, __float_as_int(x), 0x112, 0xf, 0xf, true));
  x += __int_as_float(__builtin_amdgcn_update_dpp(0, __float_as_int(x), 0x114, 0xf, 0xf, true));
  x += __int_as_float(__builtin_amdgcn_update_dpp(0, __float_as_int(x), 0x118, 0xf, 0xf, true));
  x += __int_as_float(__builtin_amdgcn_update_dpp(0, __float_as_int(x), 0x142, 0xa, 0xf, true));
  x += __int_as_float(__builtin_amdgcn_update_dpp(0, __float_as_int(x), 0x143, 0xc, 0xf, true));
  return x;
}
__device__ inline float wave_sum(float x){   // broadcast total to all lanes (sgpr)
  return __int_as_float(__builtin_amdgcn_readlane(__float_as_int(wave_sum_partial(x)), 63));
}

// pack 4 floats -> 4 fp8 e4m3 in one dword
__device__ inline unsigned pk8(float4 f){
  int r = 0;
  r = __builtin_amdgcn_cvt_pk_fp8_f32(f.x, f.y, r, false);
  r = __builtin_amdgcn_cvt_pk_fp8_f32(f.z, f.w, r, true);
  return (unsigned)r;
}
// acc += dot(4 fp8 cols in w, h)
__device__ inline float dot4_fp8(unsigned w, float4 h, float acc){
  v2f p = __builtin_amdgcn_cvt_pk_f32_fp8((int)w, false);
  acc = fmaf(p.x, h.x, acc); acc = fmaf(p.y, h.y, acc);
  p = __builtin_amdgcn_cvt_pk_f32_fp8((int)w, true);
  acc = fmaf(p.x, h.z, acc); acc = fmaf(p.y, h.w, acc);
  return acc;
}

// block = 512 threads (8 waves). Returns sums over the block to ALL threads.
__device__ inline float2 block_reduce2(float x, float y, float* red){
  float sx0 = wave_sum_partial(x), sy0 = wave_sum_partial(y);
  int w = threadIdx.x>>6;
  __syncthreads();
  if((threadIdx.x&63)==63){ red[w]=sx0; red[8+w]=sy0; }
  __syncthreads();
  float sx=0.f, sy=0.f;
  #pragma unroll
  for(int q=0;q<8;q++){ sx+=red[q]; sy+=red[8+q]; }
  return make_float2(sx,sy);
}

// ---------------- generic tiled GEMM: C[M,N] = act(A[M,K] @ B^T + bias) ----------------
template<bool BKMAJOR, bool RELU, bool KEYMAP>
__global__ __launch_bounds__(256)
void gemm_kernel(const float* __restrict__ A, const float* __restrict__ B,
                 const float* __restrict__ bias, float* __restrict__ C,
                 int M, int N, int K){
  __shared__ float As[16][64];
  __shared__ float Bs[16][64];
  const int bm = blockIdx.x, bn = blockIdx.y;
  const int t = threadIdx.x;
  const int tm = t>>4, tn = t&15;
  float acc[16];
  #pragma unroll
  for(int q=0;q<16;q++) acc[q]=0.f;

  const int ml = t>>2;          // 0..63
  const int kq = (t&3)*4;       // 0,4,8,12

  for(int k0=0;k0<K;k0+=16){
    {
      float4 av = *(const float4*)&A[(size_t)(bm*64+ml)*K + k0 + kq];
      As[kq+0][ml]=av.x; As[kq+1][ml]=av.y; As[kq+2][ml]=av.z; As[kq+3][ml]=av.w;
    }
    if(!BKMAJOR){
      float4 bv = *(const float4*)&B[(size_t)(bn*64+ml)*K + k0 + kq];
      Bs[kq+0][ml]=bv.x; Bs[kq+1][ml]=bv.y; Bs[kq+2][ml]=bv.z; Bs[kq+3][ml]=bv.w;
    } else {
      int kl = t>>4;
      int nq = (t&15)*4;
      float4 bv = *(const float4*)&B[(size_t)(k0+kl)*N + bn*64 + nq];
      *(float4*)&Bs[kl][nq] = bv;
    }
    __syncthreads();
    #pragma unroll
    for(int k=0;k<16;k++){
      float4 a4 = *(const float4*)&As[k][tm<<2];
      float4 b4 = *(const float4*)&Bs[k][tn<<2];
      float av[4] = {a4.x,a4.y,a4.z,a4.w};
      float bv[4] = {b4.x,b4.y,b4.z,b4.w};
      #pragma unroll
      for(int mi=0;mi<4;mi++)
        #pragma unroll
        for(int ni=0;ni<4;ni++)
          acc[mi*4+ni] = fmaf(av[mi], bv[ni], acc[mi*4+ni]);
    }
    __syncthreads();
  }
  #pragma unroll
  for(int mi=0;mi<4;mi++){
    int gm = (bm<<6)+(tm<<2)+mi;
    size_t orow = KEYMAP ? ((size_t)(gm>>9)*NP1 + (gm&511)) : (size_t)gm;
    #pragma unroll
    for(int ni=0;ni<4;ni++){
      int gn = (bn<<6)+(tn<<2)+ni;
      float v = acc[mi*4+ni];
      if(bias) v += bias[gn];
      if(RELU) v = fmaxf(v,0.f);
      C[orow*N + gn] = v;
    }
  }
}

// ---------------- key fixups: end-embedding row + zero row 512 ----------------
__global__ void fixup_end(const int* __restrict__ en, const float* __restrict__ end_emb,
                          float* __restrict__ key){
  int b = blockIdx.x, k = threadIdx.x;  // 128 x 128
  int e = en[b];
  key[((size_t)b*NP1 + NENT)*KDIM + k] = 0.f;
  key[((size_t)b*NP1 + e)*KDIM + k] = end_emb[k];
}

// ---------------- gather selected key rows, scaled ----------------
__global__ void gather_kr(const int* __restrict__ su, const float* __restrict__ key,
                          float* __restrict__ KR){
  int idx = blockIdx.x*256 + threadIdx.x;  // 8192*128
  int r = idx >> 7, k = idx & 127;
  int b = r >> 6;
  int s = su[r];
  KR[idx] = key[((size_t)b*NP1 + s)*KDIM + k] * INV_MAX;
}

// ---------------- c0v[f] = q1_w[f,:] . e2_b ----------------
__global__ void c0_kernel(const float* __restrict__ q1_w, const float* __restrict__ e2_b,
                          float* __restrict__ c0v){
  int f = threadIdx.x; // 1 block x 256
  float acc=0.f;
  for(int d=0;d<DIN;d+=4){
    float4 a = *(const float4*)&q1_w[(size_t)f*DIN+d];
    float4 e = *(const float4*)&e2_b[d];
    acc = fmaf(a.x,e.x,acc); acc = fmaf(a.y,e.y,acc);
    acc = fmaf(a.z,e.z,acc); acc = fmaf(a.w,e.w,acc);
  }
  c0v[f]=acc;
}

// ---------------- gated exclusive prefix over steps; emits relu(U), s1, ng ----------------
__global__ void prefix_kernel(const float* __restrict__ U0, const float* __restrict__ Q1K,
                              const float* __restrict__ c0v, const float* __restrict__ T1,
                              const int* __restrict__ su, const int* __restrict__ en,
                              const int* __restrict__ sun,
                              float* __restrict__ RU, float* __restrict__ s1,
                              float* __restrict__ ngout){
  int b = blockIdx.x, f = threadIdx.x;    // 128 x 256
  float acc = U0[b*DF+f];
  float c0f = c0v[f];
  float s1a = 0.f, ng = 0.f;
  int enb = en[b], sunb = sun[b];
  for(int j=0;j<SSTEP;j++){
    int r = b*SSTEP+j;
    float q = Q1K[(size_t)r*DF+f];
    float tt = T1[(size_t)r*DF+f];
    RU[(size_t)r*DF+f] = fmaxf(acc,0.f);
    int sj = su[r];
    float g = ((j+1)<=sunb && sj!=enb) ? 1.f : 0.f;
    acc = fmaf(g, q + c0f, acc);
    s1a = fmaf(g, tt, s1a);
    ng += g;
  }
  s1[b*DF+f]=s1a;
  if(f==0) ngout[b]=ng;
}

// ---------------- in-place LayerNorm over rows of 512 ----------------
__global__ __launch_bounds__(512)
void ln512(float* __restrict__ G, const float* __restrict__ gam, const float* __restrict__ bet){
  __shared__ float red[16];
  size_t r = blockIdx.x;
  int j = threadIdx.x;
  float v = G[r*G4+j];
  float2 s = block_reduce2(v, v*v, red);
  float mu = s.x*(1.f/512.f);
  float rs = rsqrtf(s.y*(1.f/512.f) - mu*mu + 1e-5f);
  G[r*G4+j] = (v-mu)*rs*gam[j] + bet[j];
}

// ---------------- serial 2-layer LN-LSTM scan (1 block per batch, 512 thr) ----------------
// whh0 + wih1 fp8 in LDS; whh1 fp8 in 8 uint4 regs. 4 barriers/step; all reductions
// via DPP (VALU cross-lane) instead of ds_bpermute shuffle chains.
__global__ __launch_bounds__(512)
__attribute__((amdgpu_waves_per_eu(2,2)))
void lstm_serial(const float* __restrict__ wih, const float* __restrict__ whh,
                 const float* __restrict__ G0,
                 const float* __restrict__ ln_ig, const float* __restrict__ ln_ib,
                 const float* __restrict__ ln_hg, const float* __restrict__ ln_hb,
                 const float* __restrict__ ln_cg, const float* __restrict__ ln_cb,
                 float* __restrict__ H1){
  const int b = blockIdx.x;
  const int j = threadIdx.x;
  __shared__ uint4 W0s8[8][512];       // whh0 fp8  (64 KB)
  __shared__ uint4 W1s8[8][512];       // wih1 fp8  (64 KB)
  __shared__ float h0s[128], h1s[128];
  __shared__ float pvv[512], pv1[512];
  __shared__ float lnA[512], lnB[512], lnC[512], lnD[512], lnE[512], lnF[512];
  __shared__ float red[32];

  // one-time staging: fp8-pack whh0/wih1 -> LDS, whh1 -> regs, LN tables -> LDS
  #pragma unroll
  for(int c=0;c<8;c++){
    const float* s0 = &whh[(size_t)j*KDIM + c*16];
    uint4 p;
    p.x = pk8(*(const float4*)(s0+ 0));
    p.y = pk8(*(const float4*)(s0+ 4));
    p.z = pk8(*(const float4*)(s0+ 8));
    p.w = pk8(*(const float4*)(s0+12));
    W0s8[c][j] = p;
    const float* s1 = &wih[65536 + (size_t)j*KDIM + c*16];
    uint4 q;
    q.x = pk8(*(const float4*)(s1+ 0));
    q.y = pk8(*(const float4*)(s1+ 4));
    q.z = pk8(*(const float4*)(s1+ 8));
    q.w = pk8(*(const float4*)(s1+12));
    W1s8[c][j] = q;
  }
  uint4 w2p[8];
  #pragma unroll
  for(int c=0;c<8;c++){
    const float* s2 = &whh[65536 + (size_t)j*KDIM + c*16];
    w2p[c].x = pk8(*(const float4*)(s2+ 0));
    w2p[c].y = pk8(*(const float4*)(s2+ 4));
    w2p[c].z = pk8(*(const float4*)(s2+ 8));
    w2p[c].w = pk8(*(const float4*)(s2+12));
  }
  lnA[j] = ln_hg[j];     lnB[j] = ln_hb[j];
  lnC[j] = ln_ig[512+j]; lnD[j] = ln_ib[512+j];
  lnE[j] = ln_hg[512+j]; lnF[j] = ln_hb[512+j];

  // gate-wave per-thread state (cells j and j+64), threads 0..63
  float cg0A=0.f,cb0A=0.f,cg0B=0.f,cb0B=0.f;
  float cg1A=0.f,cb1A=0.f,cg1B=0.f,cb1B=0.f;
  float c0rA=0.f,c0rB=0.f,c1rA=0.f,c1rB=0.f;
  if(j<64){
    cg0A=ln_cg[j];      cb0A=ln_cb[j];
    cg0B=ln_cg[j+64];   cb0B=ln_cb[j+64];
    cg1A=ln_cg[128+j];    cb1A=ln_cb[128+j];
    cg1B=ln_cg[128+j+64]; cb1B=ln_cb[128+j+64];
  }
  if(j<128){ h0s[j]=0.f; h1s[j]=0.f; }
  __syncthreads();

  const float4* h04 = (const float4*)h0s;
  const float4* h14 = (const float4*)h1s;
  const int w = j>>6;

  for(int i=0;i<SSTEP;i++){
    // gate-wave prefetch of this step's precomputed layer-0 input gates
    float g0a[4], g0b[4];
    if(j<64){
      const float* gp = &G0[((size_t)b*SSTEP+i)*G4];
      #pragma unroll
      for(int k=0;k<4;k++){ g0a[k]=gp[j+128*k]; g0b[k]=gp[j+64+128*k]; }
    }

    // ---- Phase A: v = whh0@h0_prev (LDS W) ; v1 = whh1@h1_prev (reg W) ----
    float v = 0.f, vb = 0.f;
    #pragma unroll
    for(int c=0;c<8;c++){
      uint4 ww = W0s8[c][j];
      v  = dot4_fp8(ww.x, h04[4*c+0], v );
      vb = dot4_fp8(ww.y, h04[4*c+1], vb);
      v  = dot4_fp8(ww.z, h04[4*c+2], v );
      vb = dot4_fp8(ww.w, h04[4*c+3], vb);
    }
    v += vb;
    float v1 = 0.f, v1b = 0.f;
    #pragma unroll
    for(int c=0;c<8;c++){
      uint4 ww = w2p[c];
      v1  = dot4_fp8(ww.x, h14[4*c+0], v1 );
      v1b = dot4_fp8(ww.y, h14[4*c+1], v1b);
      v1  = dot4_fp8(ww.z, h14[4*c+2], v1 );
      v1b = dot4_fp8(ww.w, h14[4*c+3], v1b);
    }
    v1 += v1b;
    {
      float a  = wave_sum_partial(v);
      float bq = wave_sum_partial(v*v);
      float c2 = wave_sum_partial(v1);
      float d  = wave_sum_partial(v1*v1);
      if((j&63)==63){ red[w]=a; red[8+w]=bq; red[16+w]=c2; red[24+w]=d; }
    }
    pvv[j]=v; pv1[j]=v1;
    __syncthreads();                                      // bar1

    // ---- Phase B: layer-0 gates on ONE wave (cells j, j+64) ----
    if(j<64){
      float S=0.f,S2=0.f;
      #pragma unroll
      for(int q=0;q<8;q++){ S+=red[q]; S2+=red[8+q]; }
      float mu = S*(1.f/512.f);
      float rs = rsqrtf(S2*(1.f/512.f) - mu*mu + 1e-5f);
      float ashA[4], ashB[4];
      #pragma unroll
      for(int k=0;k<4;k++){
        int ia = j + 128*k, ib = j + 64 + 128*k;
        ashA[k] = g0a[k] + (pvv[ia]-mu)*rs*lnA[ia] + lnB[ia];
        ashB[k] = g0b[k] + (pvv[ib]-mu)*rs*lnA[ib] + lnB[ib];
      }
      float cpA = sigf(ashA[1])*c0rA + sigf(ashA[0])*tanh_fast(ashA[2]);
      float cpB = sigf(ashB[1])*c0rB + sigf(ashB[0])*tanh_fast(ashB[2]);
      float s  = wave_sum(cpA+cpB);
      float s2 = wave_sum(cpA*cpA+cpB*cpB);
      float muc = s*(1.f/128.f);
      float rsc = rsqrtf(s2*(1.f/128.f) - muc*muc + 1e-5f);
      c0rA = (cpA-muc)*rsc*cg0A + cb0A;
      c0rB = (cpB-muc)*rsc*cg0B + cb0B;
      h0s[j]    = sigf(ashA[3])*tanh_fast(c0rA);
      h0s[j+64] = sigf(ashB[3])*tanh_fast(c0rB);
    }
    __syncthreads();                                      // bar2

    // ---- Phase C: u = wih1 @ h0_new (LDS W) ----
    float u = 0.f, ub = 0.f;
    #pragma unroll
    for(int c=0;c<8;c++){
      uint4 ww = W1s8[c][j];
      u  = dot4_fp8(ww.x, h04[4*c+0], u );
      ub = dot4_fp8(ww.y, h04[4*c+1], ub);
      u  = dot4_fp8(ww.z, h04[4*c+2], u );
      ub = dot4_fp8(ww.w, h04[4*c+3], ub);
    }
    u += ub;
    {
      float a  = wave_sum_partial(u);
      float bq = wave_sum_partial(u*u);
      if((j&63)==63){ red[w]=a; red[8+w]=bq; }
    }
    pvv[j]=u;                                             // reuse pvv for u
    __syncthreads();                                      // bar3

    // ---- Phase D: layer-1 gates on ONE wave ----
    if(j<64){
      float Su=0.f,Su2=0.f,Sv=0.f,Sv2=0.f;
      #pragma unroll
      for(int q=0;q<8;q++){ Su+=red[q]; Su2+=red[8+q]; Sv+=red[16+q]; Sv2+=red[24+q]; }
      float muu = Su*(1.f/512.f);
      float rsu = rsqrtf(Su2*(1.f/512.f) - muu*muu + 1e-5f);
      float muv = Sv*(1.f/512.f);
      float rsv = rsqrtf(Sv2*(1.f/512.f) - muv*muv + 1e-5f);
      float ashA[4], ashB[4];
      #pragma unroll
      for(int k=0;k<4;k++){
        int ia = j + 128*k, ib = j + 64 + 128*k;
        ashA[k] = (pvv[ia]-muu)*rsu*lnC[ia] + lnD[ia]
                + (pv1[ia]-muv)*rsv*lnE[ia] + lnF[ia];
        ashB[k] = (pvv[ib]-muu)*rsu*lnC[ib] + lnD[ib]
                + (pv1[ib]-muv)*rsv*lnE[ib] + lnF[ib];
      }
      float cpA = sigf(ashA[1])*c1rA + sigf(ashA[0])*tanh_fast(ashA[2]);
      float cpB = sigf(ashB[1])*c1rB + sigf(ashB[0])*tanh_fast(ashB[2]);
      float s  = wave_sum(cpA+cpB);
      float s2 = wave_sum(cpA*cpA+cpB*cpB);
      float muc = s*(1.f/128.f);
      float rsc = rsqrtf(s2*(1.f/128.f) - muc*muc + 1e-5f);
      c1rA = (cpA-muc)*rsc*cg1A + cb1A;
      c1rB = (cpB-muc)*rsc*cg1B + cb1B;
      float hA = sigf(ashA[3])*tanh_fast(c1rA);
      float hB = sigf(ashB[3])*tanh_fast(c1rB);
      h1s[j]    = hA;
      h1s[j+64] = hB;
      H1[((size_t)b*SSTEP+i)*HDIM + j]      = hA;
      H1[((size_t)b*SSTEP+i)*HDIM + j + 64] = hB;
    }
    __syncthreads();                                      // bar4
  }
}

// ---------------- logits: per-batch H1 @ key^T with mask ----------------
__global__ __launch_bounds__(256)
void logits_kernel(const float* __restrict__ key, const float* __restrict__ H1,
                   const int* __restrict__ en, const int* __restrict__ su,
                   float* __restrict__ out){
  const int b = blockIdx.x;
  __shared__ float HsT[128][68];       // [k][i], padded
  __shared__ int firstsel[NP1];
  for(int t=threadIdx.x; t<SSTEP*HDIM; t+=256){
    int i = t>>7, k = t&127;
    HsT[k][i] = H1[(size_t)b*SSTEP*HDIM + t];
  }
  for(int t=threadIdx.x; t<NP1; t+=256) firstsel[t] = 1<<30;
  __syncthreads();
  if(threadIdx.x < SSTEP) atomicMin(&firstsel[su[b*SSTEP+threadIdx.x]], (int)threadIdx.x);
  __syncthreads();
  const int enb = en[b];
  for(int n=threadIdx.x; n<NP1; n+=256){
    if(n > enb){
      for(int i=0;i<SSTEP;i++) out[((size_t)b*SSTEP+i)*NP1 + n] = NEGV;
      continue;
    }
    const float* kr = key + ((size_t)b*NP1 + n)*KDIM;
    const int fs = firstsel[n];
    for(int it=0; it<SSTEP; it+=16){
      float acc[16];
      #pragma unroll
      for(int q=0;q<16;q++) acc[q]=0.f;
      for(int k=0;k<KDIM;k+=4){
        float4 kv = *(const float4*)&kr[k];
        float kvs[4] = {kv.x,kv.y,kv.z,kv.w};
        #pragma unroll
        for(int kk=0;kk<4;kk++){
          #pragma unroll
          for(int qq=0;qq<4;qq++){
            float4 hv = *(const float4*)&HsT[k+kk][it+qq*4];
            acc[qq*4+0] = fmaf(kvs[kk], hv.x, acc[qq*4+0]);
            acc[qq*4+1] = fmaf(kvs[kk], hv.y, acc[qq*4+1]);
            acc[qq*4+2] = fmaf(kvs[kk], hv.z, acc[qq*4+2]);
            acc[qq*4+3] = fmaf(kvs[kk], hv.w, acc[qq*4+3]);
          }
        }
      }
      #pragma unroll
      for(int q=0;q<16;q++){
        int i = it+q;
        bool m = (fs >= i) && !(i==0 && n==enb);
        out[((size_t)b*SSTEP+i)*NP1 + n] = m ? acc[q] : NEGV;
      }
    }
  }
}

// ---------------- final ae + selected_units_num ----------------
__global__ void ae_out_kernel(const float* __restrict__ emb, const float* __restrict__ P,
                              const float* __restrict__ e2_b, const float* __restrict__ ng,
                              const int* __restrict__ sun, float* __restrict__ out){
  const size_t AE_OFF = (size_t)BSZ*SSTEP*NP1;
  const size_t SUN_OFF = AE_OFF + (size_t)BSZ*DIN;
  int idx = blockIdx.x*256+threadIdx.x;   // 131072
  int b = idx>>10, d = idx&1023;
  out[AE_OFF + idx] = emb[idx] + P[idx] + ng[b]*e2_b[d];
  if(idx < BSZ) out[SUN_OFF + idx] = (float)sun[idx];
}

// ---------------- launch ----------------
extern "C" void kernel_launch(void* const* d_in, const int* in_sizes, int n_in,
                              void* d_out, int out_size, void* d_ws, size_t ws_size,
                              hipStream_t stream){
  const float* emb     = (const float*)d_in[0];
  const float* ent     = (const float*)d_in[1];
  const float* key_w   = (const float*)d_in[2];
  const float* key_b   = (const float*)d_in[3];
  const float* q1_w    = (const float*)d_in[4];
  const float* q1_b    = (const float*)d_in[5];
  const float* q2_w    = (const float*)d_in[6];
  const float* q2_b    = (const float*)d_in[7];
  const float* e1_w    = (const float*)d_in[8];
  const float* e1_b    = (const float*)d_in[9];
  const float* e2_w    = (const float*)d_in[10];
  const float* e2_b    = (const float*)d_in[11];
  const float* end_emb = (const float*)d_in[12];
  const float* wih     = (const float*)d_in[13];
  const float* whh     = (const float*)d_in[14];
  const float* ln_ig   = (const float*)d_in[15];
  const float* ln_ib   = (const float*)d_in[16];
  const float* ln_hg   = (const float*)d_in[17];
  const float* ln_hb   = (const float*)d_in[18];
  const float* ln_cg   = (const float*)d_in[19];
  const float* ln_cb   = (const float*)d_in[20];
  const int* en  = (const int*)d_in[21];
  const int* su  = (const int*)d_in[22];
  const int* sun = (const int*)d_in[23];
  float* out = (float*)d_out;
  float* ws  = (float*)d_ws;

  // workspace layout (float units)
  const size_t o_key = 0;                       // 128*513*128 = 8,404,992
  const size_t o_KR  = o_key + 8404992;         // 1,048,576
  const size_t o_T1  = o_KR  + 1048576;         // 2,097,152
  const size_t o_q1e = o_T1  + 2097152;         // 65,536
  const size_t o_c0  = o_q1e + 65536;           // 1,024 (256 used)
  const size_t o_U0  = o_c0  + 1024;            // 32,768
  const size_t o_Q1K = o_U0  + 32768;           // 2,097,152
  const size_t o_RU  = o_Q1K + 2097152;         // 2,097,152
  const size_t o_X   = o_RU  + 2097152;         // 1,048,576
  const size_t o_G0  = o_X   + 1048576;         // 4,194,304
  const size_t o_s1  = o_G0  + 4194304;         // 32,768
  const size_t o_ng  = o_s1  + 32768;           // 1,024 (128 used)
  const size_t o_H1  = o_ng  + 1024;            // 1,048,576
  const size_t o_P   = o_H1  + 1048576;         // 131,072

  // 1) key = ent_emb @ key_w^T + key_b  (rows mapped into 513-stride layout)
  gemm_kernel<false,false,true><<<dim3(1024,2),256,0,stream>>>(ent, key_w, key_b, ws+o_key, 65536,128,256);
  // 2) end-embedding row + zero row 512
  fixup_end<<<128,128,0,stream>>>(en, end_emb, ws+o_key);
  // 3) gather selected rows / 512
  gather_kr<<<4096,256,0,stream>>>(su, ws+o_key, ws+o_KR);
  // 4) T1 = relu(KR @ e1_w^T + e1_b)
  gemm_kernel<false,true,false><<<dim3(128,4),256,0,stream>>>(ws+o_KR, e1_w, e1_b, ws+o_T1, 8192,256,128);
  // 5) q1e = q1_w @ e2_w   (fused 256x256 weight)
  gemm_kernel<true,false,false><<<dim3(4,4),256,0,stream>>>(q1_w, e2_w, nullptr, ws+o_q1e, 256,256,1024);
  // 6) c0 = q1_w @ e2_b
  c0_kernel<<<1,256,0,stream>>>(q1_w, e2_b, ws+o_c0);
  // 7) U0 = emb @ q1_w^T + q1_b
  gemm_kernel<false,false,false><<<dim3(2,4),256,0,stream>>>(emb, q1_w, q1_b, ws+o_U0, 128,256,1024);
  // 8) Q1K = T1 @ q1e^T
  gemm_kernel<false,false,false><<<dim3(128,4),256,0,stream>>>(ws+o_T1, ws+o_q1e, nullptr, ws+o_Q1K, 8192,256,256);
  // 9) gated exclusive prefix -> relu(U), s1, ng
  prefix_kernel<<<128,256,0,stream>>>(ws+o_U0, ws+o_Q1K, ws+o_c0, ws+o_T1, su, en, sun,
                                      ws+o_RU, ws+o_s1, ws+o_ng);
  // 10) X = RU @ q2_w^T + q2_b
  gemm_kernel<false,false,false><<<dim3(128,2),256,0,stream>>>(ws+o_RU, q2_w, q2_b, ws+o_X, 8192,128,256);
  // 11) G0 = X @ wih0^T ; then in-place LN with ln_ig0/ln_ib0
  gemm_kernel<false,false,false><<<dim3(128,8),256,0,stream>>>(ws+o_X, wih, nullptr, ws+o_G0, 8192,512,128);
  ln512<<<8192,512,0,stream>>>(ws+o_G0, ln_ig, ln_ib);
  // 12) serial LN-LSTM scan -> H1 (4 barriers/step, DPP reductions)
  lstm_serial<<<128,512,0,stream>>>(wih, whh, ws+o_G0,
                                    ln_ig, ln_ib, ln_hg, ln_hb, ln_cg, ln_cb, ws+o_H1);
  // 13) logits (masked) directly into d_out
  logits_kernel<<<128,256,0,stream>>>(ws+o_key, ws+o_H1, en, su, out);
  // 14) P = s1 @ e2_w^T ; ae = emb + P + ng*e2_b ; sun passthrough
  gemm_kernel<false,false,false><<<dim3(2,16),256,0,stream>>>(ws+o_s1, e2_w, nullptr, ws+o_P, 128,1024,256);
  ae_out_kernel<<<512,256,0,stream>>>(emb, ws+o_P, e2_b, ws+o_ng, sun, out);
}